// Round 1
// baseline (536.340 us; speedup 1.0000x reference)
//
#include <hip/hip_runtime.h>
#include <math.h>

namespace {

constexpr int B = 16, N = 512, H = 8, D = 32, E = 16, HID = 256;
constexpr int GH = 4;  // heads 0..GH-1 use mask[b,j]; heads GH..H-1 use focal_mask[b,i,j]
constexpr float SCALE = 0.17677669529663687f;  // 32^-0.5

// ---------------------------------------------------------------------------
// Tiled GEMM: Y = X @ W^T + bias.  X:[8192,256], W:[256,256] (out,in) row-major.
// headed=1 -> Y stored as [B,H,N,D] (n = h*32+d);  headed=0 -> Y[m,n] flat.
// ---------------------------------------------------------------------------
constexpr int BM = 64, BN = 64, BK = 16;

__global__ __launch_bounds__(256) void proj_gemm(
    const float* __restrict__ X, const float* __restrict__ W,
    const float* __restrict__ bias, float* __restrict__ Y, int headed)
{
  __shared__ __align__(16) float As[BK][BM + 4];
  __shared__ __align__(16) float Bs[BK][BN + 4];
  const int m0 = blockIdx.x * BM;
  const int n0 = blockIdx.y * BN;
  const int tx = threadIdx.x, ty = threadIdx.y;
  const int tid = ty * 16 + tx;
  const int lr = tid >> 2;        // 0..63: row (A) / out-col (B) being staged
  const int lk = (tid & 3) * 4;   // k offset within tile: 0,4,8,12
  float acc[4][4] = {};
  for (int k0 = 0; k0 < HID; k0 += BK) {
    float4 va = *(const float4*)(X + (size_t)(m0 + lr) * HID + k0 + lk);
    float4 vb = *(const float4*)(W + (size_t)(n0 + lr) * HID + k0 + lk);
    As[lk + 0][lr] = va.x; As[lk + 1][lr] = va.y; As[lk + 2][lr] = va.z; As[lk + 3][lr] = va.w;
    Bs[lk + 0][lr] = vb.x; Bs[lk + 1][lr] = vb.y; Bs[lk + 2][lr] = vb.z; Bs[lk + 3][lr] = vb.w;
    __syncthreads();
#pragma unroll
    for (int kk = 0; kk < BK; ++kk) {
      float4 a4 = *(const float4*)&As[kk][ty * 4];
      float4 b4 = *(const float4*)&Bs[kk][tx * 4];
      float a[4] = {a4.x, a4.y, a4.z, a4.w};
      float b[4] = {b4.x, b4.y, b4.z, b4.w};
#pragma unroll
      for (int i = 0; i < 4; ++i)
#pragma unroll
        for (int j = 0; j < 4; ++j)
          acc[i][j] = fmaf(a[i], b[j], acc[i][j]);
    }
    __syncthreads();
  }
#pragma unroll
  for (int i = 0; i < 4; ++i) {
    const int m = m0 + ty * 4 + i;
#pragma unroll
    for (int j = 0; j < 4; ++j) {
      const int n = n0 + tx * 4 + j;
      const float v = acc[i][j] + bias[n];
      if (headed) {
        const int b_ = m >> 9, ii = m & 511, h_ = n >> 5, d_ = n & 31;
        Y[((size_t)(b_ * H + h_) * N + ii) * D + d_] = v;
      } else {
        Y[(size_t)m * HID + n] = v;
      }
    }
  }
}

// ---------------------------------------------------------------------------
// qke[b,h,i,e] = sum_d qh[b,h,i,d]*qemb[e,h*32+d] + kh[b,h,i,d]*kemb[e,h*32+d]
// (Reference's take_along_axis gathers BOTH qe and ke at the query row i, so
//  edge_bias only needs this combined per-query-row table.)
// ---------------------------------------------------------------------------
__global__ __launch_bounds__(256) void qke_kernel(
    const float* __restrict__ qh, const float* __restrict__ kh,
    const float* __restrict__ qemb, const float* __restrict__ kemb,
    float* __restrict__ qke)
{
  __shared__ float qs[512], ks[512];
  const int t = threadIdx.x;
  const int r0 = blockIdx.x * 16;          // first of 16 rows of [B*H*N]
  const size_t base = (size_t)r0 * 32;
  for (int idx = t; idx < 512; idx += 256) {
    qs[idx] = qh[base + idx];
    ks[idx] = kh[base + idx];
  }
  __syncthreads();
  const int r = t >> 4, e = t & 15;
  const int row = r0 + r;
  const int h = (row >> 9) & 7;            // N = 512 = 2^9
  const float* qe = qemb + e * (H * D) + h * D;
  const float* ke = kemb + e * (H * D) + h * D;
  float a = 0.f;
#pragma unroll
  for (int d = 0; d < 32; ++d)
    a += qs[r * 32 + d] * qe[d] + ks[r * 32 + d] * ke[d];
  qke[(size_t)r0 * 16 + t] = a;
}

// ---------------------------------------------------------------------------
// Detect mask storage: int32 0/1 (word OR <= 1) vs raw 1-byte bool (word OR > 1).
// focal_mask has 4M random 0/1 elements -> detection is statistically certain.
// ---------------------------------------------------------------------------
__global__ __launch_bounds__(256) void detect_bool(
    const unsigned int* __restrict__ buf, int* __restrict__ flag)
{
  __shared__ unsigned int red[256];
  unsigned int v = 0;
  for (int idx = threadIdx.x; idx < 4096; idx += 256) v |= buf[idx];
  red[threadIdx.x] = v;
  __syncthreads();
  if (threadIdx.x == 0) {
    unsigned int o = 0;
    for (int i = 0; i < 256; ++i) o |= red[i];
    flag[0] = (o > 1u) ? 1 : 0;
  }
}

// ---------------------------------------------------------------------------
// Fused attention. Block = (b, h, 16 query rows). K/V staged in LDS in 64-row
// chunks (row pad 33 -> only 2-way bank aliasing, free). Full score rows in
// LDS, block softmax, PV accumulated in registers.
// ---------------------------------------------------------------------------
__global__ __launch_bounds__(256) void attn_kernel(
    const float* __restrict__ qh, const float* __restrict__ kh,
    const float* __restrict__ vh, const float* __restrict__ qke,
    const int* __restrict__ ea,
    const void* __restrict__ maskp, const void* __restrict__ fmaskp,
    const int* __restrict__ flag, float* __restrict__ ctx)
{
  __shared__ float qs[16][33];
  __shared__ float qes[16][16];
  __shared__ float kvs[64][33];
  __shared__ int   eas[16][64];
  __shared__ float p[16][513];
  __shared__ float redm[16][16];
  __shared__ float m_i[16], inv_l[16];

  const int it = blockIdx.x, h = blockIdx.y, b = blockIdx.z;
  const int i0 = it * 16;
  const int bh = b * H + h;
  const int t = threadIdx.x;
  const int bf = *flag;
  const int* mask32 = (const int*)maskp;
  const unsigned char* mask8 = (const unsigned char*)maskp;
  const int* fmask32 = (const int*)fmaskp;
  const unsigned char* fmask8 = (const unsigned char*)fmaskp;

  {  // stage Q rows + combined edge-bias rows
    const size_t qbase = ((size_t)bh * N + i0) * D;
    for (int idx = t; idx < 16 * 32; idx += 256)
      qs[idx >> 5][idx & 31] = qh[qbase + idx];
    qes[t >> 4][t & 15] = qke[((size_t)bh * N + i0) * E + t];
  }

  // ---- scores: p[i2][j] = (q.k + qke[i2][ea]) * SCALE, masked ----
  for (int jc = 0; jc < 8; ++jc) {
    __syncthreads();  // protect kvs/eas from previous chunk's readers
    {
      const size_t kb = ((size_t)bh * N + jc * 64) * D;
      for (int idx = t; idx < 64 * 32; idx += 256)
        kvs[idx >> 5][idx & 31] = kh[kb + idx];
      for (int idx = t; idx < 16 * 64; idx += 256) {
        const int i2 = idx >> 6, jj = idx & 63;
        eas[i2][jj] = ea[((size_t)(b * N) + i0 + i2) * N + jc * 64 + jj];
      }
    }
    __syncthreads();
    const int jj = t & 63;
    const int gj = jc * 64 + jj;
    int gvalid = 1;
    if (h < GH) gvalid = bf ? (int)mask8[b * N + gj] : mask32[b * N + gj];
    for (int i2 = t >> 6; i2 < 16; i2 += 4) {
      float s = 0.f;
#pragma unroll
      for (int d = 0; d < 32; ++d) s = fmaf(qs[i2][d], kvs[jj][d], s);
      s = (s + qes[i2][eas[i2][jj] & 15]) * SCALE;
      int valid = gvalid;
      if (h >= GH) {
        const size_t off = ((size_t)(b * N) + i0 + i2) * N + gj;
        valid = bf ? (int)fmask8[off] : fmask32[off];
      }
      p[i2][gj] = valid ? s : -INFINITY;
    }
  }
  __syncthreads();

  // ---- softmax per row ----
  {
    const int r = t >> 4, cc = t & 15;
    float mx = -INFINITY;
    for (int c = cc; c < 512; c += 16) mx = fmaxf(mx, p[r][c]);
    redm[r][cc] = mx;
    __syncthreads();
    if (t < 16) {
      float m2 = redm[t][0];
#pragma unroll
      for (int u = 1; u < 16; ++u) m2 = fmaxf(m2, redm[t][u]);
      m_i[t] = m2;
    }
    __syncthreads();
    const float mrow = m_i[r];
    float sm = 0.f;
    for (int c = cc; c < 512; c += 16) {
      const float ex = __expf(p[r][c] - mrow);
      p[r][c] = ex;
      sm += ex;
    }
    redm[r][cc] = sm;
    __syncthreads();
    if (t < 16) {
      float s2 = 0.f;
#pragma unroll
      for (int u = 0; u < 16; ++u) s2 += redm[t][u];
      inv_l[t] = 1.0f / s2;
    }
  }

  // ---- PV: each thread owns (row ra, dim d_) and (row ra+8, dim d_) ----
  const int d_ = t & 31, ra = t >> 5, rb = ra + 8;
  float acc0 = 0.f, acc1 = 0.f;
  for (int jc = 0; jc < 8; ++jc) {
    __syncthreads();
    {
      const size_t vb = ((size_t)bh * N + jc * 64) * D;
      for (int idx = t; idx < 64 * 32; idx += 256)
        kvs[idx >> 5][idx & 31] = vh[vb + idx];
    }
    __syncthreads();
#pragma unroll
    for (int jj = 0; jj < 64; ++jj) {
      const float vv = kvs[jj][d_];
      acc0 = fmaf(p[ra][jc * 64 + jj], vv, acc0);
      acc1 = fmaf(p[rb][jc * 64 + jj], vv, acc1);
    }
  }
  ctx[((size_t)(b * N) + i0 + ra) * HID + h * D + d_] = acc0 * inv_l[ra];
  ctx[((size_t)(b * N) + i0 + rb) * HID + h * D + d_] = acc1 * inv_l[rb];
}

}  // namespace

extern "C" void kernel_launch(void* const* d_in, const int* in_sizes, int n_in,
                              void* d_out, int out_size, void* d_ws, size_t ws_size,
                              hipStream_t stream)
{
  const float* q    = (const float*)d_in[0];
  const float* k    = (const float*)d_in[1];
  const float* v    = (const float*)d_in[2];
  const float* qemb = (const float*)d_in[3];
  const float* kemb = (const float*)d_in[4];
  const int*   ea   = (const int*)d_in[5];
  const void*  mask = d_in[6];
  const void*  fmask= d_in[7];
  const float* Wq = (const float*)d_in[8];
  const float* bq = (const float*)d_in[9];
  const float* Wk = (const float*)d_in[10];
  const float* bk = (const float*)d_in[11];
  const float* Wv = (const float*)d_in[12];
  const float* bv = (const float*)d_in[13];
  const float* Wo = (const float*)d_in[14];
  const float* bo = (const float*)d_in[15];

  // workspace layout (floats): qh|kh|vh [B,H,N,D] (2M each), qke [B,H,N,E] (1M),
  // ctx [B,N,HID] (2M), flag (1 int).  Total ~37.8 MB.
  float* ws = (float*)d_ws;
  constexpr size_t HSZ = (size_t)B * H * N * D;   // 2,097,152
  constexpr size_t QKE = (size_t)B * H * N * E;   // 1,048,576
  float* qh  = ws;
  float* kh  = qh + HSZ;
  float* vh  = kh + HSZ;
  float* qke = vh + HSZ;
  float* ctx = qke + QKE;
  int*   flag = (int*)(ctx + HSZ);

  const dim3 gb(16, 16);
  const dim3 gg((B * N) / BM, HID / BN);  // (128, 4)
  proj_gemm<<<gg, gb, 0, stream>>>(q, Wq, bq, qh, 1);
  proj_gemm<<<gg, gb, 0, stream>>>(k, Wk, bk, kh, 1);
  proj_gemm<<<gg, gb, 0, stream>>>(v, Wv, bv, vh, 1);
  detect_bool<<<1, 256, 0, stream>>>((const unsigned int*)fmask, flag);
  qke_kernel<<<(B * H * N) / 16, 256, 0, stream>>>(qh, kh, qemb, kemb, qke);
  attn_kernel<<<dim3(N / 16, H, B), 256, 0, stream>>>(qh, kh, vh, qke, ea, mask,
                                                      fmask, flag, ctx);
  proj_gemm<<<gg, gb, 0, stream>>>(ctx, Wo, bo, (float*)d_out, 0);
}

// Round 2
// 295.903 us; speedup vs baseline: 1.8126x; 1.8126x over previous
//
#include <hip/hip_runtime.h>
#include <math.h>

namespace {

constexpr int B = 16, N = 512, H = 8, D = 32, E = 16, HID = 256;
constexpr int GH = 4;  // heads 0..GH-1 use mask[b,j]; heads GH..H-1 use focal_mask[b,i,j]
constexpr float SCALE = 0.17677669529663687f;  // 32^-0.5

typedef __attribute__((ext_vector_type(8))) short short8;
typedef __attribute__((ext_vector_type(4))) float float4v;

__device__ inline short f2bf(float x) {  // fp32 -> bf16 bits, RNE (finite inputs)
  union { float f; unsigned u; } v; v.f = x;
  unsigned r = v.u + 0x7fffu + ((v.u >> 16) & 1u);
  return (short)(r >> 16);
}
__device__ inline float bf2f(unsigned short u) {
  union { unsigned u; float f; } v; v.u = ((unsigned)u) << 16; return v.f;
}

// ---------------------------------------------------------------------------
// MFMA GEMM: Y = X @ W^T + bias. X:[M,256] fp32, W:[256,256] fp32 (out,in).
// mode 0: Yf fp32 flat [M,256].  mode 1: Yh bf16 headed [B,H,N,D].
// 64x64 tile, BK=32, 4 waves in 2x2, each wave 2x2 C-frags of 16x16x32 MFMA.
// ---------------------------------------------------------------------------
__global__ __launch_bounds__(256) void gemm_mfma(
    const float* __restrict__ X, const float* __restrict__ W,
    const float* __restrict__ bias, float* __restrict__ Yf,
    unsigned short* __restrict__ Yh, int mode)
{
  __shared__ __align__(16) unsigned short As[64][40];  // pad 40 shorts (80B)
  __shared__ __align__(16) unsigned short Bs[64][40];
  const int m0 = blockIdx.x * 64, n0 = blockIdx.y * 64;
  const int t = threadIdx.x, lane = t & 63, w = t >> 6;
  const int quad = lane >> 4, col = lane & 15;
  const int wm = (w & 1) * 32, wn = (w >> 1) * 32;
  const int srow = t >> 2, skk = (t & 3) * 8;
  float4v acc[2][2] = {{{0,0,0,0},{0,0,0,0}},{{0,0,0,0},{0,0,0,0}}};

  for (int k0 = 0; k0 < HID; k0 += 32) {
    {
      const float* xp = X + (size_t)(m0 + srow) * HID + k0 + skk;
      const float* wp = W + (size_t)(n0 + srow) * HID + k0 + skk;
      float4 x1 = *(const float4*)xp, x2 = *(const float4*)(xp + 4);
      float4 w1 = *(const float4*)wp, w2 = *(const float4*)(wp + 4);
      short8 xa, wa;
      xa[0]=f2bf(x1.x); xa[1]=f2bf(x1.y); xa[2]=f2bf(x1.z); xa[3]=f2bf(x1.w);
      xa[4]=f2bf(x2.x); xa[5]=f2bf(x2.y); xa[6]=f2bf(x2.z); xa[7]=f2bf(x2.w);
      wa[0]=f2bf(w1.x); wa[1]=f2bf(w1.y); wa[2]=f2bf(w1.z); wa[3]=f2bf(w1.w);
      wa[4]=f2bf(w2.x); wa[5]=f2bf(w2.y); wa[6]=f2bf(w2.z); wa[7]=f2bf(w2.w);
      *(short8*)&As[srow][skk] = xa;
      *(short8*)&Bs[srow][skk] = wa;
    }
    __syncthreads();
    short8 a0 = *(const short8*)&As[wm + col][quad * 8];
    short8 a1 = *(const short8*)&As[wm + 16 + col][quad * 8];
    short8 b0 = *(const short8*)&Bs[wn + col][quad * 8];
    short8 b1 = *(const short8*)&Bs[wn + 16 + col][quad * 8];
    acc[0][0] = __builtin_amdgcn_mfma_f32_16x16x32_bf16(a0, b0, acc[0][0], 0, 0, 0);
    acc[0][1] = __builtin_amdgcn_mfma_f32_16x16x32_bf16(a0, b1, acc[0][1], 0, 0, 0);
    acc[1][0] = __builtin_amdgcn_mfma_f32_16x16x32_bf16(a1, b0, acc[1][0], 0, 0, 0);
    acc[1][1] = __builtin_amdgcn_mfma_f32_16x16x32_bf16(a1, b1, acc[1][1], 0, 0, 0);
    __syncthreads();
  }
#pragma unroll
  for (int mt = 0; mt < 2; ++mt)
#pragma unroll
    for (int nt = 0; nt < 2; ++nt)
#pragma unroll
      for (int r = 0; r < 4; ++r) {
        const int m = m0 + wm + mt * 16 + quad * 4 + r;
        const int n = n0 + wn + nt * 16 + col;
        const float val = acc[mt][nt][r] + bias[n];
        if (mode == 0) {
          Yf[(size_t)m * HID + n] = val;
        } else {
          const int b_ = m >> 9, ii = m & 511, h_ = n >> 5, d_ = n & 31;
          Yh[((size_t)(b_ * H + h_) * N + ii) * D + d_] = (unsigned short)f2bf(val);
        }
      }
}

// ---------------------------------------------------------------------------
// Transpose vh[b,h,n,d] -> vt[b,h,d,n] (bf16), one block per (b,h).
// ---------------------------------------------------------------------------
__global__ __launch_bounds__(256) void vtrans(
    const unsigned short* __restrict__ vh, unsigned short* __restrict__ vt)
{
  __shared__ unsigned short tile[32][522];
  const int t = threadIdx.x;
  const size_t base = (size_t)blockIdx.x * N * D;
  for (int idx = t; idx < N * D; idx += 256)
    tile[idx & 31][idx >> 5] = vh[base + idx];
  __syncthreads();
  for (int idx = t; idx < N * D; idx += 256)
    vt[base + idx] = tile[idx >> 9][idx & 511];
}

// ---------------------------------------------------------------------------
// qke[b,h,i,e] = sum_d qh*qemb + kh*kemb  (combined bias table; the reference
// gathers BOTH qe and ke at the query row i).
// ---------------------------------------------------------------------------
__global__ __launch_bounds__(256) void qke_kernel(
    const unsigned short* __restrict__ qh, const unsigned short* __restrict__ kh,
    const float* __restrict__ qemb, const float* __restrict__ kemb,
    float* __restrict__ qke)
{
  __shared__ float qs[512], ks[512];
  const int t = threadIdx.x;
  const int r0 = blockIdx.x * 16;
  const size_t base = (size_t)r0 * 32;
  for (int idx = t; idx < 512; idx += 256) {
    qs[idx] = bf2f(qh[base + idx]);
    ks[idx] = bf2f(kh[base + idx]);
  }
  __syncthreads();
  const int r = t >> 4, e = t & 15;
  const int h = ((r0 + r) >> 9) & 7;
  const float* qe = qemb + e * (H * D) + h * D;
  const float* ke = kemb + e * (H * D) + h * D;
  float a = 0.f;
#pragma unroll
  for (int d = 0; d < 32; ++d)
    a += qs[r * 32 + d] * qe[d] + ks[r * 32 + d] * ke[d];
  qke[(size_t)r0 * 16 + t] = a;
}

// ---------------------------------------------------------------------------
// Mask storage detect: int32 0/1 (word OR <= 1) vs 1-byte bool (word OR > 1).
// ---------------------------------------------------------------------------
__global__ __launch_bounds__(256) void detect_bool(
    const unsigned int* __restrict__ buf, int* __restrict__ flag)
{
  __shared__ unsigned int red[256];
  unsigned int v = 0;
  for (int idx = threadIdx.x; idx < 4096; idx += 256) v |= buf[idx];
  red[threadIdx.x] = v;
  __syncthreads();
  if (threadIdx.x == 0) {
    unsigned int o = 0;
    for (int i = 0; i < 256; ++i) o |= red[i];
    flag[0] = (o > 1u) ? 1 : 0;
  }
}

// ---------------------------------------------------------------------------
// MFMA attention. Block = (b, h, 16 queries), 4 waves; wave w owns keys
// [w*128, w*128+128) for both S and PV. Q/K/V fragments load directly from
// global bf16 (contiguous 1KB per wave-fragment). Full-row fp32 softmax in LDS.
// ---------------------------------------------------------------------------
__global__ __launch_bounds__(256) void attn_mfma(
    const unsigned short* __restrict__ qh, const unsigned short* __restrict__ kh,
    const unsigned short* __restrict__ vt, const float* __restrict__ qke,
    const int* __restrict__ ea,
    const void* __restrict__ maskp, const void* __restrict__ fmaskp,
    const int* __restrict__ flag, float* __restrict__ ctx)
{
  __shared__ float p[16][516];       // pad 516: quad bank offsets {0,16,0,16}
  __shared__ float qes[16][16];
  __shared__ float red[16][16];
  __shared__ float m_i[16], inv_l[16];
  __shared__ float ored[4][16][32];

  const int it = blockIdx.x, h = blockIdx.y, b = blockIdx.z;
  const int i0 = it * 16, bh = b * H + h;
  const int t = threadIdx.x, w = t >> 6, lane = t & 63;
  const int quad = lane >> 4, col = lane & 15;
  const int bf = *flag;
  const int* mask32 = (const int*)maskp;
  const unsigned char* mask8 = (const unsigned char*)maskp;
  const int* fmask32 = (const int*)fmaskp;
  const unsigned char* fmask8 = (const unsigned char*)fmaskp;

  qes[t >> 4][t & 15] = qke[((size_t)bh * N + i0) * E + t];
  // Q A-fragment: A[m=col][k=quad*8+j]
  const short8 qf = *(const short8*)(qh + ((size_t)bh * N + i0 + col) * D + quad * 8);
  __syncthreads();

  // ---- S = (Q.K^T + bias) * SCALE, masked -> p ----
  for (int c = 0; c < 8; ++c) {
    const int j0 = w * 128 + c * 16;
    const short8 kf = *(const short8*)(kh + ((size_t)bh * N + j0 + col) * D + quad * 8);
    float4v s = {0, 0, 0, 0};
    s = __builtin_amdgcn_mfma_f32_16x16x32_bf16(qf, kf, s, 0, 0, 0);
    const int gj = j0 + col;
    int gvalid = 1;
    if (h < GH) gvalid = bf ? (int)mask8[b * N + gj] : mask32[b * N + gj];
#pragma unroll
    for (int r = 0; r < 4; ++r) {
      const int m = quad * 4 + r;  // C layout: row = quad*4+reg, col = lane&15
      const int e = ea[((size_t)(b * N) + i0 + m) * N + gj];
      const float sv = (s[r] + qes[m][e & 15]) * SCALE;
      int valid = gvalid;
      if (h >= GH) {
        const size_t off = ((size_t)(b * N) + i0 + m) * N + gj;
        valid = bf ? (int)fmask8[off] : fmask32[off];
      }
      p[m][gj] = valid ? sv : -INFINITY;
    }
  }
  __syncthreads();

  // ---- softmax per row (exp in place, fp32) ----
  {
    const int r = t >> 4, cc = t & 15;
    float mx = -INFINITY;
    for (int c2 = cc; c2 < 512; c2 += 16) mx = fmaxf(mx, p[r][c2]);
    red[r][cc] = mx;
    __syncthreads();
    if (t < 16) {
      float m2 = red[t][0];
#pragma unroll
      for (int u = 1; u < 16; ++u) m2 = fmaxf(m2, red[t][u]);
      m_i[t] = m2;
    }
    __syncthreads();
    const float mrow = m_i[r];
    float sm = 0.f;
    for (int c2 = cc; c2 < 512; c2 += 16) {
      const float ex = __expf(p[r][c2] - mrow);
      p[r][c2] = ex;
      sm += ex;
    }
    red[r][cc] = sm;
    __syncthreads();
    if (t < 16) {
      float s2 = 0.f;
#pragma unroll
      for (int u = 0; u < 16; ++u) s2 += red[t][u];
      inv_l[t] = 1.0f / s2;
    }
  }
  __syncthreads();

  // ---- O = P.V via MFMA; wave w accumulates its 128 keys, then LDS reduce ----
  float4v o0 = {0, 0, 0, 0}, o1 = {0, 0, 0, 0};
  for (int c = 0; c < 4; ++c) {
    const int k0 = w * 128 + c * 32;
    const float* pr = &p[col][k0 + quad * 8];  // A[m=col][k]
    short8 pf;
#pragma unroll
    for (int j = 0; j < 8; ++j) pf[j] = f2bf(pr[j]);
    const short8 v0 = *(const short8*)(vt + ((size_t)bh * D + col) * N + k0 + quad * 8);
    const short8 v1 = *(const short8*)(vt + ((size_t)bh * D + 16 + col) * N + k0 + quad * 8);
    o0 = __builtin_amdgcn_mfma_f32_16x16x32_bf16(pf, v0, o0, 0, 0, 0);
    o1 = __builtin_amdgcn_mfma_f32_16x16x32_bf16(pf, v1, o1, 0, 0, 0);
  }
#pragma unroll
  for (int r = 0; r < 4; ++r) {
    ored[w][quad * 4 + r][col] = o0[r];
    ored[w][quad * 4 + r][col + 16] = o1[r];
  }
  __syncthreads();
  const int q_ = t >> 5, d_ = t & 31;
  const float a0 = ored[0][q_][d_] + ored[1][q_][d_] + ored[2][q_][d_] + ored[3][q_][d_];
  const float a1 = ored[0][q_ + 8][d_] + ored[1][q_ + 8][d_] + ored[2][q_ + 8][d_] + ored[3][q_ + 8][d_];
  ctx[((size_t)(b * N) + i0 + q_) * HID + h * D + d_] = a0 * inv_l[q_];
  ctx[((size_t)(b * N) + i0 + q_ + 8) * HID + h * D + d_] = a1 * inv_l[q_ + 8];
}

}  // namespace

extern "C" void kernel_launch(void* const* d_in, const int* in_sizes, int n_in,
                              void* d_out, int out_size, void* d_ws, size_t ws_size,
                              hipStream_t stream)
{
  const float* q    = (const float*)d_in[0];
  const float* k    = (const float*)d_in[1];
  const float* v    = (const float*)d_in[2];
  const float* qemb = (const float*)d_in[3];
  const float* kemb = (const float*)d_in[4];
  const int*   ea   = (const int*)d_in[5];
  const void*  mask = d_in[6];
  const void*  fmask= d_in[7];
  const float* Wq = (const float*)d_in[8];
  const float* bq = (const float*)d_in[9];
  const float* Wk = (const float*)d_in[10];
  const float* bk = (const float*)d_in[11];
  const float* Wv = (const float*)d_in[12];
  const float* bv = (const float*)d_in[13];
  const float* Wo = (const float*)d_in[14];
  const float* bo = (const float*)d_in[15];

  // ws layout: qh|kh|vh|vt bf16 [B,H,N,D] (4MB each), qke fp32 (4MB),
  // ctx fp32 [B,N,HID] (8MB), flag. Total ~28MB.
  unsigned short* ws16 = (unsigned short*)d_ws;
  constexpr size_t HSZ = (size_t)B * H * N * D;  // 2,097,152
  unsigned short* qhb = ws16;
  unsigned short* khb = qhb + HSZ;
  unsigned short* vhb = khb + HSZ;
  unsigned short* vtb = vhb + HSZ;
  float* qkew = (float*)(ws16 + 4 * HSZ);
  float* ctx  = qkew + (size_t)B * H * N * E;
  int*   flag = (int*)(ctx + (size_t)B * N * HID);

  const dim3 gg((B * N) / 64, HID / 64);  // (128, 4)
  gemm_mfma<<<gg, 256, 0, stream>>>(q, Wq, bq, nullptr, qhb, 1);
  gemm_mfma<<<gg, 256, 0, stream>>>(k, Wk, bk, nullptr, khb, 1);
  gemm_mfma<<<gg, 256, 0, stream>>>(v, Wv, bv, nullptr, vhb, 1);
  vtrans<<<B * H, 256, 0, stream>>>(vhb, vtb);
  detect_bool<<<1, 256, 0, stream>>>((const unsigned int*)fmask, flag);
  qke_kernel<<<(B * H * N) / 16, 256, 0, stream>>>(qhb, khb, qemb, kemb, qkew);
  attn_mfma<<<dim3(N / 16, H, B), 256, 0, stream>>>(qhb, khb, vtb, qkew, ea, mask,
                                                    fmask, flag, ctx);
  gemm_mfma<<<gg, 256, 0, stream>>>(ctx, Wo, bo, (float*)d_out, nullptr, 0);
}

// Round 3
// 273.397 us; speedup vs baseline: 1.9618x; 1.0823x over previous
//
#include <hip/hip_runtime.h>
#include <math.h>

namespace {

constexpr int B = 16, N = 512, H = 8, D = 32, E = 16, HID = 256;
constexpr int GH = 4;  // heads 0..GH-1 use mask[b,j]; heads GH..H-1 use focal_mask[b,i,j]
constexpr float SCALE = 0.17677669529663687f;  // 32^-0.5

typedef __attribute__((ext_vector_type(8))) short short8;
typedef __attribute__((ext_vector_type(4))) float float4v;

__device__ inline short f2bf(float x) {  // fp32 -> bf16 bits, RNE (finite inputs)
  union { float f; unsigned u; } v; v.f = x;
  unsigned r = v.u + 0x7fffu + ((v.u >> 16) & 1u);
  return (short)(r >> 16);
}
__device__ inline float bf2f(unsigned short u) {
  union { unsigned u; float f; } v; v.u = ((unsigned)u) << 16; return v.f;
}

// ---------------------------------------------------------------------------
// Fused Q/K/V projection GEMM: z selects input/weight/bias. Y bf16 headed
// [B,H,N,D]. 64x64 tile, BK=32, 4 waves 2x2, each wave 2x2 16x16x32 C-frags.
// ---------------------------------------------------------------------------
__global__ __launch_bounds__(256) void gemm_qkv(
    const float* __restrict__ Xq, const float* __restrict__ Xk, const float* __restrict__ Xv,
    const float* __restrict__ Wq, const float* __restrict__ Wk, const float* __restrict__ Wv,
    const float* __restrict__ bq, const float* __restrict__ bk, const float* __restrict__ bv,
    unsigned short* __restrict__ Ybase)
{
  __shared__ __align__(16) unsigned short As[64][40];
  __shared__ __align__(16) unsigned short Bs[64][40];
  const int z = blockIdx.z;
  const float* X = (z == 0) ? Xq : (z == 1) ? Xk : Xv;
  const float* W = (z == 0) ? Wq : (z == 1) ? Wk : Wv;
  const float* bias = (z == 0) ? bq : (z == 1) ? bk : bv;
  unsigned short* Yh = Ybase + (size_t)z * ((size_t)B * H * N * D);

  const int m0 = blockIdx.x * 64, n0 = blockIdx.y * 64;
  const int t = threadIdx.x, lane = t & 63, w = t >> 6;
  const int quad = lane >> 4, col = lane & 15;
  const int wm = (w & 1) * 32, wn = (w >> 1) * 32;
  const int srow = t >> 2, skk = (t & 3) * 8;
  float4v acc[2][2] = {{{0,0,0,0},{0,0,0,0}},{{0,0,0,0},{0,0,0,0}}};

  for (int k0 = 0; k0 < HID; k0 += 32) {
    {
      const float* xp = X + (size_t)(m0 + srow) * HID + k0 + skk;
      const float* wp = W + (size_t)(n0 + srow) * HID + k0 + skk;
      float4 x1 = *(const float4*)xp, x2 = *(const float4*)(xp + 4);
      float4 w1 = *(const float4*)wp, w2 = *(const float4*)(wp + 4);
      short8 xa, wa;
      xa[0]=f2bf(x1.x); xa[1]=f2bf(x1.y); xa[2]=f2bf(x1.z); xa[3]=f2bf(x1.w);
      xa[4]=f2bf(x2.x); xa[5]=f2bf(x2.y); xa[6]=f2bf(x2.z); xa[7]=f2bf(x2.w);
      wa[0]=f2bf(w1.x); wa[1]=f2bf(w1.y); wa[2]=f2bf(w1.z); wa[3]=f2bf(w1.w);
      wa[4]=f2bf(w2.x); wa[5]=f2bf(w2.y); wa[6]=f2bf(w2.z); wa[7]=f2bf(w2.w);
      *(short8*)&As[srow][skk] = xa;
      *(short8*)&Bs[srow][skk] = wa;
    }
    __syncthreads();
    short8 a0 = *(const short8*)&As[wm + col][quad * 8];
    short8 a1 = *(const short8*)&As[wm + 16 + col][quad * 8];
    short8 b0 = *(const short8*)&Bs[wn + col][quad * 8];
    short8 b1 = *(const short8*)&Bs[wn + 16 + col][quad * 8];
    acc[0][0] = __builtin_amdgcn_mfma_f32_16x16x32_bf16(a0, b0, acc[0][0], 0, 0, 0);
    acc[0][1] = __builtin_amdgcn_mfma_f32_16x16x32_bf16(a0, b1, acc[0][1], 0, 0, 0);
    acc[1][0] = __builtin_amdgcn_mfma_f32_16x16x32_bf16(a1, b0, acc[1][0], 0, 0, 0);
    acc[1][1] = __builtin_amdgcn_mfma_f32_16x16x32_bf16(a1, b1, acc[1][1], 0, 0, 0);
    __syncthreads();
  }
#pragma unroll
  for (int mt = 0; mt < 2; ++mt)
#pragma unroll
    for (int nt = 0; nt < 2; ++nt)
#pragma unroll
      for (int r = 0; r < 4; ++r) {
        const int m = m0 + wm + mt * 16 + quad * 4 + r;
        const int n = n0 + wn + nt * 16 + col;
        const float val = acc[mt][nt][r] + bias[n];
        const int b_ = m >> 9, ii = m & 511, h_ = n >> 5, d_ = n & 31;
        Yh[((size_t)(b_ * H + h_) * N + ii) * D + d_] = (unsigned short)f2bf(val);
      }
}

// ---------------------------------------------------------------------------
// Output GEMM: Y = X(bf16) @ W^T + bias, fp32 flat out.
// ---------------------------------------------------------------------------
__global__ __launch_bounds__(256) void gemm_out(
    const unsigned short* __restrict__ X, const float* __restrict__ W,
    const float* __restrict__ bias, float* __restrict__ Yf)
{
  __shared__ __align__(16) unsigned short As[64][40];
  __shared__ __align__(16) unsigned short Bs[64][40];
  const int m0 = blockIdx.x * 64, n0 = blockIdx.y * 64;
  const int t = threadIdx.x, lane = t & 63, w = t >> 6;
  const int quad = lane >> 4, col = lane & 15;
  const int wm = (w & 1) * 32, wn = (w >> 1) * 32;
  const int srow = t >> 2, skk = (t & 3) * 8;
  float4v acc[2][2] = {{{0,0,0,0},{0,0,0,0}},{{0,0,0,0},{0,0,0,0}}};

  for (int k0 = 0; k0 < HID; k0 += 32) {
    {
      *(short8*)&As[srow][skk] =
          *(const short8*)(X + (size_t)(m0 + srow) * HID + k0 + skk);
      const float* wp = W + (size_t)(n0 + srow) * HID + k0 + skk;
      float4 w1 = *(const float4*)wp, w2 = *(const float4*)(wp + 4);
      short8 wa;
      wa[0]=f2bf(w1.x); wa[1]=f2bf(w1.y); wa[2]=f2bf(w1.z); wa[3]=f2bf(w1.w);
      wa[4]=f2bf(w2.x); wa[5]=f2bf(w2.y); wa[6]=f2bf(w2.z); wa[7]=f2bf(w2.w);
      *(short8*)&Bs[srow][skk] = wa;
    }
    __syncthreads();
    short8 a0 = *(const short8*)&As[wm + col][quad * 8];
    short8 a1 = *(const short8*)&As[wm + 16 + col][quad * 8];
    short8 b0 = *(const short8*)&Bs[wn + col][quad * 8];
    short8 b1 = *(const short8*)&Bs[wn + 16 + col][quad * 8];
    acc[0][0] = __builtin_amdgcn_mfma_f32_16x16x32_bf16(a0, b0, acc[0][0], 0, 0, 0);
    acc[0][1] = __builtin_amdgcn_mfma_f32_16x16x32_bf16(a0, b1, acc[0][1], 0, 0, 0);
    acc[1][0] = __builtin_amdgcn_mfma_f32_16x16x32_bf16(a1, b0, acc[1][0], 0, 0, 0);
    acc[1][1] = __builtin_amdgcn_mfma_f32_16x16x32_bf16(a1, b1, acc[1][1], 0, 0, 0);
    __syncthreads();
  }
#pragma unroll
  for (int mt = 0; mt < 2; ++mt)
#pragma unroll
    for (int nt = 0; nt < 2; ++nt)
#pragma unroll
      for (int r = 0; r < 4; ++r) {
        const int m = m0 + wm + mt * 16 + quad * 4 + r;
        const int n = n0 + wn + nt * 16 + col;
        Yf[(size_t)m * HID + n] = acc[mt][nt][r] + bias[n];
      }
}

// ---------------------------------------------------------------------------
// Transpose vh[b,h,n,d] -> vt[b,h,d,n] (bf16), one block per (b,h).
// ---------------------------------------------------------------------------
__global__ __launch_bounds__(256) void vtrans(
    const unsigned short* __restrict__ vh, unsigned short* __restrict__ vt)
{
  __shared__ unsigned short tile[32][522];
  const int t = threadIdx.x;
  const size_t base = (size_t)blockIdx.x * N * D;
  for (int idx = t; idx < N * D; idx += 256)
    tile[idx & 31][idx >> 5] = vh[base + idx];
  __syncthreads();
  for (int idx = t; idx < N * D; idx += 256)
    vt[base + idx] = tile[idx >> 9][idx & 511];
}

// ---------------------------------------------------------------------------
// qke[b,h,i,e] = sum_d qh*qemb + kh*kemb  (reference gathers BOTH qe and ke
// at the query row i, so only this combined per-row table is needed).
// ---------------------------------------------------------------------------
__global__ __launch_bounds__(256) void qke_kernel(
    const unsigned short* __restrict__ qh, const unsigned short* __restrict__ kh,
    const float* __restrict__ qemb, const float* __restrict__ kemb,
    float* __restrict__ qke)
{
  __shared__ float qs[512], ks[512];
  const int t = threadIdx.x;
  const int r0 = blockIdx.x * 16;
  const size_t base = (size_t)r0 * 32;
  for (int idx = t; idx < 512; idx += 256) {
    qs[idx] = bf2f(qh[base + idx]);
    ks[idx] = bf2f(kh[base + idx]);
  }
  __syncthreads();
  const int r = t >> 4, e = t & 15;
  const int h = ((r0 + r) >> 9) & 7;
  const float* qe = qemb + e * (H * D) + h * D;
  const float* ke = kemb + e * (H * D) + h * D;
  float a = 0.f;
#pragma unroll
  for (int d = 0; d < 32; ++d)
    a += qs[r * 32 + d] * qe[d] + ks[r * 32 + d] * ke[d];
  qke[(size_t)r0 * 16 + t] = a;
}

// ---------------------------------------------------------------------------
// Mask storage detect: int32 0/1 (word OR <= 1) vs 1-byte bool (word OR > 1).
// ---------------------------------------------------------------------------
__global__ __launch_bounds__(256) void detect_bool(
    const unsigned int* __restrict__ buf, int* __restrict__ flag)
{
  __shared__ unsigned int red[256];
  unsigned int v = 0;
  for (int idx = threadIdx.x; idx < 4096; idx += 256) v |= buf[idx];
  red[threadIdx.x] = v;
  __syncthreads();
  if (threadIdx.x == 0) {
    unsigned int o = 0;
    for (int i = 0; i < 256; ++i) o |= red[i];
    flag[0] = (o > 1u) ? 1 : 0;
  }
}

// ---------------------------------------------------------------------------
// MFMA attention, register-resident softmax. Block = (b,h,16 queries), 4
// waves; wave w owns keys [w*128, w*128+128). Scores stay in 32 VGPRs through
// bias/mask/softmax (row reductions via shfl_xor within 16-lane quad groups,
// cross-wave via tiny LDS). One LDS round-trip: exp'd P as bf16 for the
// C-layout -> A-layout transform. 4 barriers total. LDS ~26 KB -> 6 blk/CU.
// ---------------------------------------------------------------------------
__global__ __launch_bounds__(256) void attn_mfma(
    const unsigned short* __restrict__ qh, const unsigned short* __restrict__ kh,
    const unsigned short* __restrict__ vt, const float* __restrict__ qke,
    const int* __restrict__ ea,
    const void* __restrict__ maskp, const void* __restrict__ fmaskp,
    const int* __restrict__ flag, unsigned short* __restrict__ ctx)
{
  __shared__ __align__(16) unsigned short P[16][520];  // pitch 1040B: 16B-aligned rows
  __shared__ float qes[16][16];
  __shared__ float wmax[4][16];
  __shared__ float wsum[4][16];
  __shared__ float ored[4][16][32];

  const int it = blockIdx.x, h = blockIdx.y, b = blockIdx.z;
  const int i0 = it * 16, bh = b * H + h;
  const int t = threadIdx.x, w = t >> 6, lane = t & 63;
  const int quad = lane >> 4, col = lane & 15;
  const int bf = *flag;
  const int* mask32 = (const int*)maskp;
  const unsigned char* mask8 = (const unsigned char*)maskp;
  const int* fmask32 = (const int*)fmaskp;
  const unsigned char* fmask8 = (const unsigned char*)fmaskp;

  qes[t >> 4][t & 15] = qke[((size_t)bh * N + i0) * E + t];
  const short8 qf = *(const short8*)(qh + ((size_t)bh * N + i0 + col) * D + quad * 8);
  __syncthreads();

  // ---- S = (Q.K^T + bias)*SCALE, masked; stays in registers ----
  float s[8][4];
#pragma unroll
  for (int c = 0; c < 8; ++c) {
    const int j0 = w * 128 + c * 16;
    const short8 kf = *(const short8*)(kh + ((size_t)bh * N + j0 + col) * D + quad * 8);
    float4v sc = {0, 0, 0, 0};
    sc = __builtin_amdgcn_mfma_f32_16x16x32_bf16(qf, kf, sc, 0, 0, 0);
    const int gj = j0 + col;
    int gvalid = 1;
    if (h < GH) gvalid = bf ? (int)mask8[b * N + gj] : mask32[b * N + gj];
#pragma unroll
    for (int r = 0; r < 4; ++r) {
      const int m = quad * 4 + r;  // C layout: row = quad*4+reg, col = lane&15
      const size_t off = ((size_t)(b * N) + i0 + m) * N + gj;
      const int e = ea[off] & 15;
      const float sv = (sc[r] + qes[m][e]) * SCALE;
      int valid = gvalid;
      if (h >= GH) valid = bf ? (int)fmask8[off] : fmask32[off];
      s[c][r] = valid ? sv : -INFINITY;
    }
  }

  // ---- row max: in-lane over 8 chunks, then shfl over the 16 col-lanes ----
  if (col == 0) { /* placeholder to keep wmax defined before use */ }
#pragma unroll
  for (int r = 0; r < 4; ++r) {
    float m2 = s[0][r];
#pragma unroll
    for (int c = 1; c < 8; ++c) m2 = fmaxf(m2, s[c][r]);
    m2 = fmaxf(m2, __shfl_xor(m2, 1));
    m2 = fmaxf(m2, __shfl_xor(m2, 2));
    m2 = fmaxf(m2, __shfl_xor(m2, 4));
    m2 = fmaxf(m2, __shfl_xor(m2, 8));
    if (col == 0) wmax[w][quad * 4 + r] = m2;
  }
  __syncthreads();

  // ---- exp in regs, write bf16 P, accumulate row sums ----
  float sm[4] = {0.f, 0.f, 0.f, 0.f};
#pragma unroll
  for (int r = 0; r < 4; ++r) {
    const int m = quad * 4 + r;
    const float rm = fmaxf(fmaxf(wmax[0][m], wmax[1][m]), fmaxf(wmax[2][m], wmax[3][m]));
#pragma unroll
    for (int c = 0; c < 8; ++c) {
      const float ex = __expf(s[c][r] - rm);
      sm[r] += ex;
      P[m][w * 128 + c * 16 + col] = (unsigned short)f2bf(ex);
    }
  }
#pragma unroll
  for (int r = 0; r < 4; ++r) {
    float t2 = sm[r];
    t2 += __shfl_xor(t2, 1);
    t2 += __shfl_xor(t2, 2);
    t2 += __shfl_xor(t2, 4);
    t2 += __shfl_xor(t2, 8);
    if (col == 0) wsum[w][quad * 4 + r] = t2;
  }
  __syncthreads();

  // ---- O = P.V (wave-local 128 keys), LDS reduce across waves ----
  float4v o0 = {0, 0, 0, 0}, o1 = {0, 0, 0, 0};
#pragma unroll
  for (int c2 = 0; c2 < 4; ++c2) {
    const int k0 = w * 128 + c2 * 32;
    const short8 pf = *(const short8*)&P[col][k0 + quad * 8];  // A[m=col][k]
    const short8 v0 = *(const short8*)(vt + ((size_t)bh * D + col) * N + k0 + quad * 8);
    const short8 v1 = *(const short8*)(vt + ((size_t)bh * D + 16 + col) * N + k0 + quad * 8);
    o0 = __builtin_amdgcn_mfma_f32_16x16x32_bf16(pf, v0, o0, 0, 0, 0);
    o1 = __builtin_amdgcn_mfma_f32_16x16x32_bf16(pf, v1, o1, 0, 0, 0);
  }
#pragma unroll
  for (int r = 0; r < 4; ++r) {
    ored[w][quad * 4 + r][col] = o0[r];
    ored[w][quad * 4 + r][col + 16] = o1[r];
  }
  __syncthreads();
  const int q_ = t >> 5, d_ = t & 31;
  const float l0 = wsum[0][q_] + wsum[1][q_] + wsum[2][q_] + wsum[3][q_];
  const float l1 = wsum[0][q_ + 8] + wsum[1][q_ + 8] + wsum[2][q_ + 8] + wsum[3][q_ + 8];
  const float a0 = ored[0][q_][d_] + ored[1][q_][d_] + ored[2][q_][d_] + ored[3][q_][d_];
  const float a1 = ored[0][q_ + 8][d_] + ored[1][q_ + 8][d_] + ored[2][q_ + 8][d_] + ored[3][q_ + 8][d_];
  ctx[((size_t)(b * N) + i0 + q_) * HID + h * D + d_] = (unsigned short)f2bf(a0 / l0);
  ctx[((size_t)(b * N) + i0 + q_ + 8) * HID + h * D + d_] = (unsigned short)f2bf(a1 / l1);
}

}  // namespace

extern "C" void kernel_launch(void* const* d_in, const int* in_sizes, int n_in,
                              void* d_out, int out_size, void* d_ws, size_t ws_size,
                              hipStream_t stream)
{
  const float* q    = (const float*)d_in[0];
  const float* k    = (const float*)d_in[1];
  const float* v    = (const float*)d_in[2];
  const float* qemb = (const float*)d_in[3];
  const float* kemb = (const float*)d_in[4];
  const int*   ea   = (const int*)d_in[5];
  const void*  mask = d_in[6];
  const void*  fmask= d_in[7];
  const float* Wq = (const float*)d_in[8];
  const float* bq = (const float*)d_in[9];
  const float* Wk = (const float*)d_in[10];
  const float* bk = (const float*)d_in[11];
  const float* Wv = (const float*)d_in[12];
  const float* bv = (const float*)d_in[13];
  const float* Wo = (const float*)d_in[14];
  const float* bo = (const float*)d_in[15];

  // ws: qh|kh|vh|vt bf16 [B,H,N,D] (4MB ea), qke fp32 (4MB), ctx bf16 (4MB), flag.
  unsigned short* ws16 = (unsigned short*)d_ws;
  constexpr size_t HSZ = (size_t)B * H * N * D;  // 2,097,152
  unsigned short* qhb = ws16;
  unsigned short* khb = qhb + HSZ;
  unsigned short* vhb = khb + HSZ;
  unsigned short* vtb = vhb + HSZ;
  float* qkew = (float*)(ws16 + 4 * HSZ);
  unsigned short* ctx = (unsigned short*)(qkew + (size_t)B * H * N * E);
  int* flag = (int*)(ctx + (size_t)B * N * HID);

  gemm_qkv<<<dim3((B * N) / 64, HID / 64, 3), 256, 0, stream>>>(
      q, k, v, Wq, Wk, Wv, bq, bk, bv, qhb);
  vtrans<<<B * H, 256, 0, stream>>>(vhb, vtb);
  detect_bool<<<1, 256, 0, stream>>>((const unsigned int*)fmask, flag);
  qke_kernel<<<(B * H * N) / 16, 256, 0, stream>>>(qhb, khb, qemb, kemb, qkew);
  attn_mfma<<<dim3(N / 16, H, B), 256, 0, stream>>>(qhb, khb, vtb, qkew, ea, mask,
                                                    fmask, flag, ctx);
  gemm_out<<<dim3((B * N) / 64, HID / 64), 256, 0, stream>>>(ctx, Wo, bo, (float*)d_out);
}

// Round 5
// 226.540 us; speedup vs baseline: 2.3675x; 1.2068x over previous
//
#include <hip/hip_runtime.h>
#include <math.h>

namespace {

constexpr int B = 16, N = 512, H = 8, D = 32, E = 16, HID = 256;
constexpr float SCALE = 0.17677669529663687f;  // 32^-0.5

typedef __attribute__((ext_vector_type(8))) short short8;
typedef __attribute__((ext_vector_type(4))) float float4v;

__device__ inline short f2bf(float x) {  // fp32 -> bf16 bits, RNE (finite inputs)
  union { float f; unsigned u; } v; v.f = x;
  unsigned r = v.u + 0x7fffu + ((v.u >> 16) & 1u);
  return (short)(r >> 16);
}
__device__ inline float bf2f(unsigned short u) {
  union { unsigned u; float f; } v; v.u = ((unsigned)u) << 16; return v.f;
}

// ---------------------------------------------------------------------------
// Fused Q/K/V projection GEMM (z selects). Y bf16 headed [B,H,N,D].
// 64x64 tile, BK=64 (4 K-iters, 8 barriers total).
// ---------------------------------------------------------------------------
__global__ __launch_bounds__(256) void gemm_qkv(
    const float* __restrict__ Xq, const float* __restrict__ Xk, const float* __restrict__ Xv,
    const float* __restrict__ Wq, const float* __restrict__ Wk, const float* __restrict__ Wv,
    const float* __restrict__ bq, const float* __restrict__ bk, const float* __restrict__ bv,
    unsigned short* __restrict__ Ybase)
{
  __shared__ __align__(16) unsigned short As[64][72];
  __shared__ __align__(16) unsigned short Bs[64][72];
  const int z = blockIdx.z;
  const float* X = (z == 0) ? Xq : (z == 1) ? Xk : Xv;
  const float* W = (z == 0) ? Wq : (z == 1) ? Wk : Wv;
  const float* bias = (z == 0) ? bq : (z == 1) ? bk : bv;
  unsigned short* Yh = Ybase + (size_t)z * ((size_t)B * H * N * D);

  const int m0 = blockIdx.x * 64, n0 = blockIdx.y * 64;
  const int t = threadIdx.x, lane = t & 63, w = t >> 6;
  const int quad = lane >> 4, col = lane & 15;
  const int wm = (w & 1) * 32, wn = (w >> 1) * 32;
  const int srow = t >> 2, skk = (t & 3) * 16;
  float4v acc[2][2] = {{{0,0,0,0},{0,0,0,0}},{{0,0,0,0},{0,0,0,0}}};

  for (int kit = 0; kit < 4; ++kit) {
    const int k0 = kit * 64;
    {
      const float* xp = X + (size_t)(m0 + srow) * HID + k0 + skk;
      const float* wp = W + (size_t)(n0 + srow) * HID + k0 + skk;
      float4 x1 = *(const float4*)xp, x2 = *(const float4*)(xp + 4);
      float4 x3 = *(const float4*)(xp + 8), x4 = *(const float4*)(xp + 12);
      float4 w1 = *(const float4*)wp, w2 = *(const float4*)(wp + 4);
      float4 w3 = *(const float4*)(wp + 8), w4 = *(const float4*)(wp + 12);
      short8 xa, xb, wa, wb;
      xa[0]=f2bf(x1.x); xa[1]=f2bf(x1.y); xa[2]=f2bf(x1.z); xa[3]=f2bf(x1.w);
      xa[4]=f2bf(x2.x); xa[5]=f2bf(x2.y); xa[6]=f2bf(x2.z); xa[7]=f2bf(x2.w);
      xb[0]=f2bf(x3.x); xb[1]=f2bf(x3.y); xb[2]=f2bf(x3.z); xb[3]=f2bf(x3.w);
      xb[4]=f2bf(x4.x); xb[5]=f2bf(x4.y); xb[6]=f2bf(x4.z); xb[7]=f2bf(x4.w);
      wa[0]=f2bf(w1.x); wa[1]=f2bf(w1.y); wa[2]=f2bf(w1.z); wa[3]=f2bf(w1.w);
      wa[4]=f2bf(w2.x); wa[5]=f2bf(w2.y); wa[6]=f2bf(w2.z); wa[7]=f2bf(w2.w);
      wb[0]=f2bf(w3.x); wb[1]=f2bf(w3.y); wb[2]=f2bf(w3.z); wb[3]=f2bf(w3.w);
      wb[4]=f2bf(w4.x); wb[5]=f2bf(w4.y); wb[6]=f2bf(w4.z); wb[7]=f2bf(w4.w);
      *(short8*)&As[srow][skk] = xa; *(short8*)&As[srow][skk + 8] = xb;
      *(short8*)&Bs[srow][skk] = wa; *(short8*)&Bs[srow][skk + 8] = wb;
    }
    __syncthreads();
#pragma unroll
    for (int ks = 0; ks < 2; ++ks) {
      const int kk = ks * 32 + quad * 8;
      short8 a0 = *(const short8*)&As[wm + col][kk];
      short8 a1 = *(const short8*)&As[wm + 16 + col][kk];
      short8 b0 = *(const short8*)&Bs[wn + col][kk];
      short8 b1 = *(const short8*)&Bs[wn + 16 + col][kk];
      acc[0][0] = __builtin_amdgcn_mfma_f32_16x16x32_bf16(a0, b0, acc[0][0], 0, 0, 0);
      acc[0][1] = __builtin_amdgcn_mfma_f32_16x16x32_bf16(a0, b1, acc[0][1], 0, 0, 0);
      acc[1][0] = __builtin_amdgcn_mfma_f32_16x16x32_bf16(a1, b0, acc[1][0], 0, 0, 0);
      acc[1][1] = __builtin_amdgcn_mfma_f32_16x16x32_bf16(a1, b1, acc[1][1], 0, 0, 0);
    }
    __syncthreads();
  }
#pragma unroll
  for (int mt = 0; mt < 2; ++mt)
#pragma unroll
    for (int nt = 0; nt < 2; ++nt)
#pragma unroll
      for (int r = 0; r < 4; ++r) {
        const int m = m0 + wm + mt * 16 + quad * 4 + r;
        const int n = n0 + wn + nt * 16 + col;
        const float val = acc[mt][nt][r] + bias[n];
        const int b_ = m >> 9, ii = m & 511, h_ = n >> 5, d_ = n & 31;
        Yh[((size_t)(b_ * H + h_) * N + ii) * D + d_] = (unsigned short)f2bf(val);
      }
}

// ---------------------------------------------------------------------------
// Output GEMM: Y = X(bf16) @ W^T + bias, fp32 flat out. BK=64.
// ---------------------------------------------------------------------------
__global__ __launch_bounds__(256) void gemm_out(
    const unsigned short* __restrict__ X, const float* __restrict__ W,
    const float* __restrict__ bias, float* __restrict__ Yf)
{
  __shared__ __align__(16) unsigned short As[64][72];
  __shared__ __align__(16) unsigned short Bs[64][72];
  const int m0 = blockIdx.x * 64, n0 = blockIdx.y * 64;
  const int t = threadIdx.x, lane = t & 63, w = t >> 6;
  const int quad = lane >> 4, col = lane & 15;
  const int wm = (w & 1) * 32, wn = (w >> 1) * 32;
  const int srow = t >> 2, skk = (t & 3) * 16;
  float4v acc[2][2] = {{{0,0,0,0},{0,0,0,0}},{{0,0,0,0},{0,0,0,0}}};

  for (int kit = 0; kit < 4; ++kit) {
    const int k0 = kit * 64;
    {
      const unsigned short* xp = X + (size_t)(m0 + srow) * HID + k0 + skk;
      *(short8*)&As[srow][skk] = *(const short8*)xp;
      *(short8*)&As[srow][skk + 8] = *(const short8*)(xp + 8);
      const float* wp = W + (size_t)(n0 + srow) * HID + k0 + skk;
      float4 w1 = *(const float4*)wp, w2 = *(const float4*)(wp + 4);
      float4 w3 = *(const float4*)(wp + 8), w4 = *(const float4*)(wp + 12);
      short8 wa, wb;
      wa[0]=f2bf(w1.x); wa[1]=f2bf(w1.y); wa[2]=f2bf(w1.z); wa[3]=f2bf(w1.w);
      wa[4]=f2bf(w2.x); wa[5]=f2bf(w2.y); wa[6]=f2bf(w2.z); wa[7]=f2bf(w2.w);
      wb[0]=f2bf(w3.x); wb[1]=f2bf(w3.y); wb[2]=f2bf(w3.z); wb[3]=f2bf(w3.w);
      wb[4]=f2bf(w4.x); wb[5]=f2bf(w4.y); wb[6]=f2bf(w4.z); wb[7]=f2bf(w4.w);
      *(short8*)&Bs[srow][skk] = wa; *(short8*)&Bs[srow][skk + 8] = wb;
    }
    __syncthreads();
#pragma unroll
    for (int ks = 0; ks < 2; ++ks) {
      const int kk = ks * 32 + quad * 8;
      short8 a0 = *(const short8*)&As[wm + col][kk];
      short8 a1 = *(const short8*)&As[wm + 16 + col][kk];
      short8 b0 = *(const short8*)&Bs[wn + col][kk];
      short8 b1 = *(const short8*)&Bs[wn + 16 + col][kk];
      acc[0][0] = __builtin_amdgcn_mfma_f32_16x16x32_bf16(a0, b0, acc[0][0], 0, 0, 0);
      acc[0][1] = __builtin_amdgcn_mfma_f32_16x16x32_bf16(a0, b1, acc[0][1], 0, 0, 0);
      acc[1][0] = __builtin_amdgcn_mfma_f32_16x16x32_bf16(a1, b0, acc[1][0], 0, 0, 0);
      acc[1][1] = __builtin_amdgcn_mfma_f32_16x16x32_bf16(a1, b1, acc[1][1], 0, 0, 0);
    }
    __syncthreads();
  }
#pragma unroll
  for (int mt = 0; mt < 2; ++mt)
#pragma unroll
    for (int nt = 0; nt < 2; ++nt)
#pragma unroll
      for (int r = 0; r < 4; ++r) {
        const int m = m0 + wm + mt * 16 + quad * 4 + r;
        const int n = n0 + wn + nt * 16 + col;
        Yf[(size_t)m * HID + n] = acc[mt][nt][r] + bias[n];
      }
}

// ---------------------------------------------------------------------------
// Transpose vh[b,h,n,d] -> vt[b,h,d,n] (bf16), one block per (b,h).
// ---------------------------------------------------------------------------
__global__ __launch_bounds__(256) void vtrans(
    const unsigned short* __restrict__ vh, unsigned short* __restrict__ vt)
{
  __shared__ unsigned short tile[32][522];
  const int t = threadIdx.x;
  const size_t base = (size_t)blockIdx.x * N * D;
  for (int idx = t; idx < N * D; idx += 256)
    tile[idx & 31][idx >> 5] = vh[base + idx];
  __syncthreads();
  for (int idx = t; idx < N * D; idx += 256)
    vt[base + idx] = tile[idx >> 9][idx & 511];
}

// ---------------------------------------------------------------------------
// qke[b,h,i,e] = sum_d qh*qemb + kh*kemb  (reference gathers BOTH qe and ke
// at the query row i, so only this combined per-row table is needed).
// ---------------------------------------------------------------------------
__global__ __launch_bounds__(256) void qke_kernel(
    const unsigned short* __restrict__ qh, const unsigned short* __restrict__ kh,
    const float* __restrict__ qemb, const float* __restrict__ kemb,
    float* __restrict__ qke)
{
  __shared__ float qs[512], ks[512];
  const int t = threadIdx.x;
  const int r0 = blockIdx.x * 16;
  const size_t base = (size_t)r0 * 32;
  for (int idx = t; idx < 512; idx += 256) {
    qs[idx] = bf2f(qh[base + idx]);
    ks[idx] = bf2f(kh[base + idx]);
  }
  __syncthreads();
  const int r = t >> 4, e = t & 15;
  const int h = ((r0 + r) >> 9) & 7;
  const float* qe = qemb + e * (H * D) + h * D;
  const float* ke = kemb + e * (H * D) + h * D;
  float a = 0.f;
#pragma unroll
  for (int d = 0; d < 32; ++d)
    a += qs[r * 32 + d] * qe[d] + ks[r * 32 + d] * ke[d];
  qke[(size_t)r0 * 16 + t] = a;
}

// ---------------------------------------------------------------------------
// Mask storage detect (shfl-reduced): int32 0/1 (word OR <= 1) vs byte bools.
// ---------------------------------------------------------------------------
__global__ __launch_bounds__(256) void detect_bool(
    const unsigned int* __restrict__ buf, int* __restrict__ flag)
{
  __shared__ unsigned wr[4];
  const int t = threadIdx.x, w = t >> 6, lane = t & 63;
  unsigned v = 0;
  for (int idx = t; idx < 4096; idx += 256) v |= buf[idx];
  v |= __shfl_xor(v, 1);  v |= __shfl_xor(v, 2);  v |= __shfl_xor(v, 4);
  v |= __shfl_xor(v, 8);  v |= __shfl_xor(v, 16); v |= __shfl_xor(v, 32);
  if (lane == 0) wr[w] = v;
  __syncthreads();
  if (t == 0) flag[0] = ((wr[0] | wr[1] | wr[2] | wr[3]) > 1u) ? 1 : 0;
}

// ---------------------------------------------------------------------------
// Pack per-pair byte tensor: packed[b][itile][j][m] = e | focal<<4 | mask<<5
// (m = query row within 16-tile). Tile-transposed so attention stages it as
// straight 16B-per-row copies and reads one u32 per 4 score elements.
// ---------------------------------------------------------------------------
__global__ __launch_bounds__(256) void pack_kernel(
    const int* __restrict__ ea, const void* __restrict__ maskp,
    const void* __restrict__ fmaskp, const int* __restrict__ flag,
    unsigned char* __restrict__ packed)
{
  __shared__ unsigned char tl[16 * 520];
  const int it = blockIdx.x, b = blockIdx.y, t = threadIdx.x;
  const int i0 = it * 16;
  const int bf = *flag;
  const int* fm32 = (const int*)fmaskp;
  const unsigned char* fm8 = (const unsigned char*)fmaskp;
  const int* mk32 = (const int*)maskp;
  const unsigned char* mk8 = (const unsigned char*)maskp;

  for (int idx = t; idx < 16 * 512; idx += 256) {
    const int m = idx >> 9, j = idx & 511;
    const size_t goff = ((size_t)(b * N) + i0 + m) * N + j;
    const int e = ea[goff] & 15;
    const int fv = bf ? (int)fm8[goff] : fm32[goff];
    const int mv = bf ? (int)mk8[b * N + j] : mk32[b * N + j];
    tl[m * 520 + j] = (unsigned char)(e | (fv ? 16 : 0) | (mv ? 32 : 0));
  }
  __syncthreads();
#pragma unroll
  for (int rep = 0; rep < 2; ++rep) {
    const int j = t * 2 + rep;
    unsigned wd[4];
#pragma unroll
    for (int g = 0; g < 4; ++g) {
      const unsigned b0 = tl[(g * 4 + 0) * 520 + j];
      const unsigned b1 = tl[(g * 4 + 1) * 520 + j];
      const unsigned b2 = tl[(g * 4 + 2) * 520 + j];
      const unsigned b3 = tl[(g * 4 + 3) * 520 + j];
      wd[g] = b0 | (b1 << 8) | (b2 << 16) | (b3 << 24);
    }
    *(uint4*)(packed + ((size_t)(b * 32 + it) * 512 + j) * 16) =
        make_uint4(wd[0], wd[1], wd[2], wd[3]);
  }
}

// ---------------------------------------------------------------------------
// MFMA attention, head-pair per block, wave-autonomous online softmax.
// Block = (itile, pair p, b); heads (p, p+4). Wave w owns keys [w*128,+128)
// for both heads: S-MFMA -> wave-local softmax (shfl) -> P in wave-private
// LDS (per-wave in-order LDS, no barrier) -> PV-MFMA. Cross-wave merge via
// exp-rescale. 3 barriers total, zero per-element global loads.
// P row pitch 136 shorts (272B, 16B-aligned): wave slice is 16x128, +8 pad.
// ---------------------------------------------------------------------------
__global__ __launch_bounds__(256, 3) void attn_mfma(
    const unsigned short* __restrict__ qh, const unsigned short* __restrict__ kh,
    const unsigned short* __restrict__ vt, const float* __restrict__ qke,
    const unsigned char* __restrict__ packed, unsigned short* __restrict__ ctx)
{
  __shared__ __align__(16) unsigned char tileT[512 * 16];   // [j][m] bytes
  __shared__ __align__(16) unsigned short P[4][16][136];    // wave-private P
  __shared__ float qesS[2][16][17];
  __shared__ float ored[4][2][16][33];
  __shared__ float2 wlm[4][2][16];
  __shared__ float scl[4][32];
  __shared__ float linv[32];

  const int it = blockIdx.x, p = blockIdx.y, b = blockIdx.z;
  const int i0 = it * 16;
  const int t = threadIdx.x, w = t >> 6, lane = t & 63;
  const int quad = lane >> 4, col = lane & 15;

  // wave-private staging of the packed tile rows this wave will read
  {
    const unsigned char* pt = packed + ((size_t)(b * 32 + it) * 512) * 16;
    const int j0s = w * 128 + lane;
    *(uint4*)&tileT[(size_t)j0s * 16] = *(const uint4*)(pt + (size_t)j0s * 16);
    *(uint4*)&tileT[(size_t)(j0s + 64) * 16] =
        *(const uint4*)(pt + (size_t)(j0s + 64) * 16);
  }
  // cooperative qes staging (SCALE folded)
#pragma unroll
  for (int rep = 0; rep < 2; ++rep) {
    const int vi = rep * 256 + t;
    const int h2 = vi >> 8, m = (vi >> 4) & 15, e = vi & 15;
    qesS[h2][m][e] =
        qke[((size_t)(b * H + p + h2 * 4) * N + i0 + m) * E + e] * SCALE;
  }
  __syncthreads();

#pragma unroll
  for (int h2 = 0; h2 < 2; ++h2) {
    const int bh = b * H + p + h2 * 4;
    const short8 qf = *(const short8*)(qh + ((size_t)bh * N + i0 + col) * D + quad * 8);

    // ---- S for this wave's 128 keys ----
    float s[8][4];
#pragma unroll
    for (int c = 0; c < 8; ++c) {
      const int j0 = w * 128 + c * 16;
      const short8 kf = *(const short8*)(kh + ((size_t)bh * N + j0 + col) * D + quad * 8);
      float4v sc = {0, 0, 0, 0};
      sc = __builtin_amdgcn_mfma_f32_16x16x32_bf16(qf, kf, sc, 0, 0, 0);
      const unsigned pk = *(const unsigned*)&tileT[(size_t)(j0 + col) * 16 + quad * 4];
#pragma unroll
      for (int r = 0; r < 4; ++r) {
        const int m = quad * 4 + r;
        const unsigned by = pk >> (8 * r);
        const int e = by & 15;
        const int valid = h2 ? (by >> 4) & 1 : (by >> 5) & 1;
        const float sv = fmaf(sc[r], SCALE, qesS[h2][m][e]);
        s[c][r] = valid ? sv : -INFINITY;
      }
    }

    // ---- wave-local softmax over 128 keys ----
    float mW[4];
#pragma unroll
    for (int r = 0; r < 4; ++r) {
      float m2 = s[0][r];
#pragma unroll
      for (int c = 1; c < 8; ++c) m2 = fmaxf(m2, s[c][r]);
      m2 = fmaxf(m2, __shfl_xor(m2, 1));
      m2 = fmaxf(m2, __shfl_xor(m2, 2));
      m2 = fmaxf(m2, __shfl_xor(m2, 4));
      m2 = fmaxf(m2, __shfl_xor(m2, 8));
      mW[r] = fmaxf(m2, -3.0e38f);
    }
#pragma unroll
    for (int r = 0; r < 4; ++r) {
      const int m = quad * 4 + r;
      float sm = 0.f;
#pragma unroll
      for (int c = 0; c < 8; ++c) {
        const float ex = __expf(s[c][r] - mW[r]);
        sm += ex;
        P[w][m][c * 16 + col] = (unsigned short)f2bf(ex);
      }
      sm += __shfl_xor(sm, 1);
      sm += __shfl_xor(sm, 2);
      sm += __shfl_xor(sm, 4);
      sm += __shfl_xor(sm, 8);
      if (col == 0) wlm[w][h2][m] = make_float2(mW[r], sm);
    }

    // ---- PV over this wave's 128 keys (P wave-private: no barrier) ----
    float4v o0 = {0, 0, 0, 0}, o1 = {0, 0, 0, 0};
#pragma unroll
    for (int c2 = 0; c2 < 4; ++c2) {
      const int kl = c2 * 32 + quad * 8;
      const short8 pf = *(const short8*)&P[w][col][kl];
      const int kg = w * 128 + kl;
      const short8 v0 = *(const short8*)(vt + ((size_t)bh * D + col) * N + kg);
      const short8 v1 = *(const short8*)(vt + ((size_t)bh * D + 16 + col) * N + kg);
      o0 = __builtin_amdgcn_mfma_f32_16x16x32_bf16(pf, v0, o0, 0, 0, 0);
      o1 = __builtin_amdgcn_mfma_f32_16x16x32_bf16(pf, v1, o1, 0, 0, 0);
    }
#pragma unroll
    for (int r = 0; r < 4; ++r) {
      ored[w][h2][quad * 4 + r][col] = o0[r];
      ored[w][h2][quad * 4 + r][col + 16] = o1[r];
    }
  }
  __syncthreads();

  // ---- cross-wave merge: scales from wave-local (m,l) ----
  if (t < 128) {
    const int u = t & 3, row = t >> 2, h2 = row >> 4, q = row & 15;
    const float2 s0 = wlm[0][h2][q], s1 = wlm[1][h2][q];
    const float2 s2 = wlm[2][h2][q], s3 = wlm[3][h2][q];
    const float mg = fmaxf(fmaxf(s0.x, s1.x), fmaxf(s2.x, s3.x));
    const float2 sw = (u == 0) ? s0 : (u == 1) ? s1 : (u == 2) ? s2 : s3;
    scl[u][row] = __expf(sw.x - mg);
    if (u == 0) {
      const float ls = s0.y * __expf(s0.x - mg) + s1.y * __expf(s1.x - mg) +
                       s2.y * __expf(s2.x - mg) + s3.y * __expf(s3.x - mg);
      linv[row] = 1.0f / ls;
    }
  }
  __syncthreads();

#pragma unroll
  for (int it2 = 0; it2 < 4; ++it2) {
    const int flat = it2 * 256 + t;
    const int h2 = flat >> 9, rem = flat & 511, q = rem >> 5, d = rem & 31;
    const int row = h2 * 16 + q;
    const float val = ored[0][h2][q][d] * scl[0][row] +
                      ored[1][h2][q][d] * scl[1][row] +
                      ored[2][h2][q][d] * scl[2][row] +
                      ored[3][h2][q][d] * scl[3][row];
    ctx[((size_t)(b * N) + i0 + q) * HID + (p + h2 * 4) * D + d] =
        (unsigned short)f2bf(val * linv[row]);
  }
}

}  // namespace

extern "C" void kernel_launch(void* const* d_in, const int* in_sizes, int n_in,
                              void* d_out, int out_size, void* d_ws, size_t ws_size,
                              hipStream_t stream)
{
  const float* q    = (const float*)d_in[0];
  const float* k    = (const float*)d_in[1];
  const float* v    = (const float*)d_in[2];
  const float* qemb = (const float*)d_in[3];
  const float* kemb = (const float*)d_in[4];
  const int*   ea   = (const int*)d_in[5];
  const void*  mask = d_in[6];
  const void*  fmask= d_in[7];
  const float* Wq = (const float*)d_in[8];
  const float* bq = (const float*)d_in[9];
  const float* Wk = (const float*)d_in[10];
  const float* bk = (const float*)d_in[11];
  const float* Wv = (const float*)d_in[12];
  const float* bv = (const float*)d_in[13];
  const float* Wo = (const float*)d_in[14];
  const float* bo = (const float*)d_in[15];

  // ws: qh|kh|vh|vt bf16 (4MB ea), qke fp32 (4MB), ctx bf16 (4MB),
  // packed u8 [B][32][512][16] (4MB), flag.
  unsigned short* ws16 = (unsigned short*)d_ws;
  constexpr size_t HSZ = (size_t)B * H * N * D;  // 2,097,152
  unsigned short* qhb = ws16;
  unsigned short* khb = qhb + HSZ;
  unsigned short* vhb = khb + HSZ;
  unsigned short* vtb = vhb + HSZ;
  float* qkew = (float*)(ws16 + 4 * HSZ);
  unsigned short* ctx = (unsigned short*)(qkew + (size_t)B * H * N * E);
  unsigned char* packed = (unsigned char*)(ctx + (size_t)B * N * HID);
  int* flag = (int*)(packed + (size_t)B * N * N);

  gemm_qkv<<<dim3((B * N) / 64, HID / 64, 3), 256, 0, stream>>>(
      q, k, v, Wq, Wk, Wv, bq, bk, bv, qhb);
  detect_bool<<<1, 256, 0, stream>>>((const unsigned int*)fmask, flag);
  pack_kernel<<<dim3(N / 16, B), 256, 0, stream>>>(ea, mask, fmask, flag, packed);
  vtrans<<<B * H, 256, 0, stream>>>(vhb, vtb);
  qke_kernel<<<(B * H * N) / 16, 256, 0, stream>>>(qhb, khb, qemb, kemb, qkew);
  attn_mfma<<<dim3(N / 16, H / 2, B), 256, 0, stream>>>(qhb, khb, vtb, qkew,
                                                        packed, ctx);
  gemm_out<<<dim3((B * N) / 64, HID / 64), 256, 0, stream>>>(ctx, Wo, bo, (float*)d_out);
}

// Round 6
// 212.274 us; speedup vs baseline: 2.5266x; 1.0672x over previous
//
#include <hip/hip_runtime.h>
#include <math.h>

namespace {

constexpr int B = 16, N = 512, H = 8, D = 32, E = 16, HID = 256;
constexpr float SCALE = 0.17677669529663687f;  // 32^-0.5
constexpr size_t HSZ = (size_t)B * H * N * D;  // 2,097,152 elements (= B*N*HID)
constexpr size_t WSZ = (size_t)HID * HID;      // 65,536

typedef __attribute__((ext_vector_type(8))) short short8;
typedef __attribute__((ext_vector_type(4))) float float4v;

__device__ inline short f2bf(float x) {  // fp32 -> bf16 bits, RNE (finite inputs)
  union { float f; unsigned u; } v; v.f = x;
  unsigned r = v.u + 0x7fffu + ((v.u >> 16) & 1u);
  return (short)(r >> 16);
}
__device__ inline float bf2f(unsigned short u) {
  union { unsigned u; float f; } v; v.u = ((unsigned)u) << 16; return v.f;
}

// ---------------------------------------------------------------------------
// One-shot fp32->bf16 conversion of q,k,v,Wq,Wk,Wv,Wo (exact grid: 6400 blocks
// x 256 threads x 4 elems). Last block (6400) instead runs the mask-storage
// detector: int32 0/1 data ORs to <=1, byte-packed bools OR to >1.
// ---------------------------------------------------------------------------
__global__ __launch_bounds__(256) void convert_kernel(
    const float* __restrict__ q, const float* __restrict__ k, const float* __restrict__ v,
    const float* __restrict__ Wq, const float* __restrict__ Wk,
    const float* __restrict__ Wv, const float* __restrict__ Wo,
    unsigned short* __restrict__ qx, unsigned short* __restrict__ kx,
    unsigned short* __restrict__ vx, unsigned short* __restrict__ wq,
    unsigned short* __restrict__ wk, unsigned short* __restrict__ wv,
    unsigned short* __restrict__ wo,
    const unsigned* __restrict__ fmask_u32, int* __restrict__ flag)
{
  if (blockIdx.x == gridDim.x - 1) {
    __shared__ unsigned wr[4];
    const int t = threadIdx.x, w = t >> 6, lane = t & 63;
    unsigned o = 0;
    for (int idx = t; idx < 4096; idx += 256) o |= fmask_u32[idx];
    o |= __shfl_xor(o, 1);  o |= __shfl_xor(o, 2);  o |= __shfl_xor(o, 4);
    o |= __shfl_xor(o, 8);  o |= __shfl_xor(o, 16); o |= __shfl_xor(o, 32);
    if (lane == 0) wr[w] = o;
    __syncthreads();
    if (t == 0) flag[0] = ((wr[0] | wr[1] | wr[2] | wr[3]) > 1u) ? 1 : 0;
    return;
  }
  constexpr size_t H4 = HSZ / 4;   // 524288 quads
  constexpr size_t W4 = WSZ / 4;   // 16384 quads
  const size_t idx = (size_t)blockIdx.x * 256 + threadIdx.x;
  const float* src; unsigned short* dst; size_t off;
  if (idx < H4)            { src = q; dst = qx; off = idx; }
  else if (idx < 2 * H4)   { src = k; dst = kx; off = idx - H4; }
  else if (idx < 3 * H4)   { src = v; dst = vx; off = idx - 2 * H4; }
  else {
    const size_t r = idx - 3 * H4;
    const int wsel = (int)(r / W4); off = r % W4;
    src = (wsel == 0) ? Wq : (wsel == 1) ? Wk : (wsel == 2) ? Wv : Wo;
    dst = (wsel == 0) ? wq : (wsel == 1) ? wk : (wsel == 2) ? wv : wo;
  }
  const float4 f = ((const float4*)src)[off];
  ushort4 o;
  o.x = (unsigned short)f2bf(f.x); o.y = (unsigned short)f2bf(f.y);
  o.z = (unsigned short)f2bf(f.z); o.w = (unsigned short)f2bf(f.w);
  ((ushort4*)dst)[off] = o;
}

// ---------------------------------------------------------------------------
// Fused Q/K/V projection GEMM, all-bf16 staging. z=0 -> qh headed [B,H,N,D],
// z=1 -> kh headed, z=2 -> V written TRANSPOSED [B,H,D,N] (vt) directly.
// 64x64 tile, BK=64.
// ---------------------------------------------------------------------------
__global__ __launch_bounds__(256) void gemm_qkv(
    const unsigned short* __restrict__ Xq, const unsigned short* __restrict__ Xk,
    const unsigned short* __restrict__ Xv,
    const unsigned short* __restrict__ Wq, const unsigned short* __restrict__ Wk,
    const unsigned short* __restrict__ Wv,
    const float* __restrict__ bq, const float* __restrict__ bk,
    const float* __restrict__ bv,
    unsigned short* __restrict__ qh, unsigned short* __restrict__ kh,
    unsigned short* __restrict__ vt)
{
  __shared__ __align__(16) unsigned short As[64][72];
  __shared__ __align__(16) unsigned short Bs[64][72];
  const int z = blockIdx.z;
  const unsigned short* X = (z == 0) ? Xq : (z == 1) ? Xk : Xv;
  const unsigned short* W = (z == 0) ? Wq : (z == 1) ? Wk : Wv;
  const float* bias = (z == 0) ? bq : (z == 1) ? bk : bv;

  const int m0 = blockIdx.x * 64, n0 = blockIdx.y * 64;
  const int t = threadIdx.x, lane = t & 63, w = t >> 6;
  const int quad = lane >> 4, col = lane & 15;
  const int wm = (w & 1) * 32, wn = (w >> 1) * 32;
  const int srow = t >> 2, skk = (t & 3) * 16;
  float4v acc[2][2] = {{{0,0,0,0},{0,0,0,0}},{{0,0,0,0},{0,0,0,0}}};

  for (int kit = 0; kit < 4; ++kit) {
    const int k0 = kit * 64;
    {
      const unsigned short* xp = X + (size_t)(m0 + srow) * HID + k0 + skk;
      const unsigned short* wp = W + (size_t)(n0 + srow) * HID + k0 + skk;
      *(short8*)&As[srow][skk] = *(const short8*)xp;
      *(short8*)&As[srow][skk + 8] = *(const short8*)(xp + 8);
      *(short8*)&Bs[srow][skk] = *(const short8*)wp;
      *(short8*)&Bs[srow][skk + 8] = *(const short8*)(wp + 8);
    }
    __syncthreads();
#pragma unroll
    for (int ks = 0; ks < 2; ++ks) {
      const int kk = ks * 32 + quad * 8;
      short8 a0 = *(const short8*)&As[wm + col][kk];
      short8 a1 = *(const short8*)&As[wm + 16 + col][kk];
      short8 b0 = *(const short8*)&Bs[wn + col][kk];
      short8 b1 = *(const short8*)&Bs[wn + 16 + col][kk];
      acc[0][0] = __builtin_amdgcn_mfma_f32_16x16x32_bf16(a0, b0, acc[0][0], 0, 0, 0);
      acc[0][1] = __builtin_amdgcn_mfma_f32_16x16x32_bf16(a0, b1, acc[0][1], 0, 0, 0);
      acc[1][0] = __builtin_amdgcn_mfma_f32_16x16x32_bf16(a1, b0, acc[1][0], 0, 0, 0);
      acc[1][1] = __builtin_amdgcn_mfma_f32_16x16x32_bf16(a1, b1, acc[1][1], 0, 0, 0);
    }
    __syncthreads();
  }
#pragma unroll
  for (int mt = 0; mt < 2; ++mt)
#pragma unroll
    for (int nt = 0; nt < 2; ++nt)
#pragma unroll
      for (int r = 0; r < 4; ++r) {
        const int m = m0 + wm + mt * 16 + quad * 4 + r;
        const int n = n0 + wn + nt * 16 + col;
        const float val = acc[mt][nt][r] + bias[n];
        const int b_ = m >> 9, ii = m & 511, h_ = n >> 5, d_ = n & 31;
        if (z == 2) {
          // transposed: vt[b,h,d,n] (L2 merges the per-lane 2B scatters; the
          // block's line footprint equals its data size)
          vt[((size_t)(b_ * H + h_) * D + d_) * N + ii] = (unsigned short)f2bf(val);
        } else {
          unsigned short* Yh = (z == 0) ? qh : kh;
          Yh[((size_t)(b_ * H + h_) * N + ii) * D + d_] = (unsigned short)f2bf(val);
        }
      }
}

// ---------------------------------------------------------------------------
// Output GEMM: Y = ctx(bf16) @ Wo^T(bf16) + bias, fp32 flat out. BK=64.
// ---------------------------------------------------------------------------
__global__ __launch_bounds__(256) void gemm_out(
    const unsigned short* __restrict__ X, const unsigned short* __restrict__ W,
    const float* __restrict__ bias, float* __restrict__ Yf)
{
  __shared__ __align__(16) unsigned short As[64][72];
  __shared__ __align__(16) unsigned short Bs[64][72];
  const int m0 = blockIdx.x * 64, n0 = blockIdx.y * 64;
  const int t = threadIdx.x, lane = t & 63, w = t >> 6;
  const int quad = lane >> 4, col = lane & 15;
  const int wm = (w & 1) * 32, wn = (w >> 1) * 32;
  const int srow = t >> 2, skk = (t & 3) * 16;
  float4v acc[2][2] = {{{0,0,0,0},{0,0,0,0}},{{0,0,0,0},{0,0,0,0}}};

  for (int kit = 0; kit < 4; ++kit) {
    const int k0 = kit * 64;
    {
      const unsigned short* xp = X + (size_t)(m0 + srow) * HID + k0 + skk;
      const unsigned short* wp = W + (size_t)(n0 + srow) * HID + k0 + skk;
      *(short8*)&As[srow][skk] = *(const short8*)xp;
      *(short8*)&As[srow][skk + 8] = *(const short8*)(xp + 8);
      *(short8*)&Bs[srow][skk] = *(const short8*)wp;
      *(short8*)&Bs[srow][skk + 8] = *(const short8*)(wp + 8);
    }
    __syncthreads();
#pragma unroll
    for (int ks = 0; ks < 2; ++ks) {
      const int kk = ks * 32 + quad * 8;
      short8 a0 = *(const short8*)&As[wm + col][kk];
      short8 a1 = *(const short8*)&As[wm + 16 + col][kk];
      short8 b0 = *(const short8*)&Bs[wn + col][kk];
      short8 b1 = *(const short8*)&Bs[wn + 16 + col][kk];
      acc[0][0] = __builtin_amdgcn_mfma_f32_16x16x32_bf16(a0, b0, acc[0][0], 0, 0, 0);
      acc[0][1] = __builtin_amdgcn_mfma_f32_16x16x32_bf16(a0, b1, acc[0][1], 0, 0, 0);
      acc[1][0] = __builtin_amdgcn_mfma_f32_16x16x32_bf16(a1, b0, acc[1][0], 0, 0, 0);
      acc[1][1] = __builtin_amdgcn_mfma_f32_16x16x32_bf16(a1, b1, acc[1][1], 0, 0, 0);
    }
    __syncthreads();
  }
#pragma unroll
  for (int mt = 0; mt < 2; ++mt)
#pragma unroll
    for (int nt = 0; nt < 2; ++nt)
#pragma unroll
      for (int r = 0; r < 4; ++r) {
        const int m = m0 + wm + mt * 16 + quad * 4 + r;
        const int n = n0 + wn + nt * 16 + col;
        Yf[(size_t)m * HID + n] = acc[mt][nt][r] + bias[n];
      }
}

// ---------------------------------------------------------------------------
// qke[b,h,i,e] = sum_d qh*qemb + kh*kemb  (reference gathers BOTH qe and ke
// at the query row i, so only this combined per-row table is needed).
// ---------------------------------------------------------------------------
__global__ __launch_bounds__(256) void qke_kernel(
    const unsigned short* __restrict__ qh, const unsigned short* __restrict__ kh,
    const float* __restrict__ qemb, const float* __restrict__ kemb,
    float* __restrict__ qke)
{
  __shared__ float qs[512], ks[512];
  const int t = threadIdx.x;
  const int r0 = blockIdx.x * 16;
  const size_t base = (size_t)r0 * 32;
  for (int idx = t; idx < 512; idx += 256) {
    qs[idx] = bf2f(qh[base + idx]);
    ks[idx] = bf2f(kh[base + idx]);
  }
  __syncthreads();
  const int r = t >> 4, e = t & 15;
  const int h = ((r0 + r) >> 9) & 7;
  const float* qe = qemb + e * (H * D) + h * D;
  const float* ke = kemb + e * (H * D) + h * D;
  float a = 0.f;
#pragma unroll
  for (int d = 0; d < 32; ++d)
    a += qs[r * 32 + d] * qe[d] + ks[r * 32 + d] * ke[d];
  qke[(size_t)r0 * 16 + t] = a;
}

// ---------------------------------------------------------------------------
// Pack per-pair byte tensor: packed[b][itile][j][m] = e | focal<<4 | mask<<5.
// Vectorized: int4 ea loads, u32 mask loads, u32 LDS writes.
// ---------------------------------------------------------------------------
__global__ __launch_bounds__(256) void pack_kernel(
    const int* __restrict__ ea, const void* __restrict__ maskp,
    const void* __restrict__ fmaskp, const int* __restrict__ flag,
    unsigned char* __restrict__ packed)
{
  __shared__ unsigned char tl[16 * 520];
  const int it = blockIdx.x, b = blockIdx.y, t = threadIdx.x;
  const int i0 = it * 16;
  const int bf = *flag;
  const int* fm32 = (const int*)fmaskp;
  const unsigned char* fm8 = (const unsigned char*)fmaskp;
  const int* mk32 = (const int*)maskp;
  const unsigned char* mk8 = (const unsigned char*)maskp;

  for (int idx4 = t; idx4 < 2048; idx4 += 256) {
    const int m = idx4 >> 7, j4 = (idx4 & 127) * 4;
    const size_t rowoff = ((size_t)(b * N) + i0 + m) * N;
    const int4 e4 = *(const int4*)(ea + rowoff + j4);
    int fv0, fv1, fv2, fv3, mv0, mv1, mv2, mv3;
    if (bf) {
      const unsigned fw = *(const unsigned*)(fm8 + rowoff + j4);
      fv0 = fw & 0xff; fv1 = (fw >> 8) & 0xff; fv2 = (fw >> 16) & 0xff; fv3 = fw >> 24;
      const unsigned mw = *(const unsigned*)(mk8 + b * N + j4);
      mv0 = mw & 0xff; mv1 = (mw >> 8) & 0xff; mv2 = (mw >> 16) & 0xff; mv3 = mw >> 24;
    } else {
      const int4 fw = *(const int4*)(fm32 + rowoff + j4);
      fv0 = fw.x; fv1 = fw.y; fv2 = fw.z; fv3 = fw.w;
      const int4 mw = *(const int4*)(mk32 + b * N + j4);
      mv0 = mw.x; mv1 = mw.y; mv2 = mw.z; mv3 = mw.w;
    }
    const unsigned b0 = (e4.x & 15) | (fv0 ? 16u : 0u) | (mv0 ? 32u : 0u);
    const unsigned b1 = (e4.y & 15) | (fv1 ? 16u : 0u) | (mv1 ? 32u : 0u);
    const unsigned b2 = (e4.z & 15) | (fv2 ? 16u : 0u) | (mv2 ? 32u : 0u);
    const unsigned b3 = (e4.w & 15) | (fv3 ? 16u : 0u) | (mv3 ? 32u : 0u);
    *(unsigned*)&tl[m * 520 + j4] = b0 | (b1 << 8) | (b2 << 16) | (b3 << 24);
  }
  __syncthreads();
#pragma unroll
  for (int rep = 0; rep < 2; ++rep) {
    const int j = t * 2 + rep;
    unsigned wd[4];
#pragma unroll
    for (int g = 0; g < 4; ++g) {
      const unsigned c0 = tl[(g * 4 + 0) * 520 + j];
      const unsigned c1 = tl[(g * 4 + 1) * 520 + j];
      const unsigned c2 = tl[(g * 4 + 2) * 520 + j];
      const unsigned c3 = tl[(g * 4 + 3) * 520 + j];
      wd[g] = c0 | (c1 << 8) | (c2 << 16) | (c3 << 24);
    }
    *(uint4*)(packed + ((size_t)(b * 32 + it) * 512 + j) * 16) =
        make_uint4(wd[0], wd[1], wd[2], wd[3]);
  }
}

// ---------------------------------------------------------------------------
// MFMA attention, head-pair per block, wave-autonomous online softmax.
// Block = (itile, pair p, b); heads (p, p+4). Wave w owns keys [w*128,+128)
// for both heads. 3 barriers, zero per-element global loads.
// ---------------------------------------------------------------------------
__global__ __launch_bounds__(256, 3) void attn_mfma(
    const unsigned short* __restrict__ qh, const unsigned short* __restrict__ kh,
    const unsigned short* __restrict__ vt, const float* __restrict__ qke,
    const unsigned char* __restrict__ packed, unsigned short* __restrict__ ctx)
{
  __shared__ __align__(16) unsigned char tileT[512 * 16];   // [j][m] bytes
  __shared__ __align__(16) unsigned short P[4][16][136];    // wave-private P
  __shared__ float qesS[2][16][17];
  __shared__ float ored[4][2][16][33];
  __shared__ float2 wlm[4][2][16];
  __shared__ float scl[4][32];
  __shared__ float linv[32];

  const int it = blockIdx.x, p = blockIdx.y, b = blockIdx.z;
  const int i0 = it * 16;
  const int t = threadIdx.x, w = t >> 6, lane = t & 63;
  const int quad = lane >> 4, col = lane & 15;

  {
    const unsigned char* pt = packed + ((size_t)(b * 32 + it) * 512) * 16;
    const int j0s = w * 128 + lane;
    *(uint4*)&tileT[(size_t)j0s * 16] = *(const uint4*)(pt + (size_t)j0s * 16);
    *(uint4*)&tileT[(size_t)(j0s + 64) * 16] =
        *(const uint4*)(pt + (size_t)(j0s + 64) * 16);
  }
#pragma unroll
  for (int rep = 0; rep < 2; ++rep) {
    const int vi = rep * 256 + t;
    const int h2 = vi >> 8, m = (vi >> 4) & 15, e = vi & 15;
    qesS[h2][m][e] =
        qke[((size_t)(b * H + p + h2 * 4) * N + i0 + m) * E + e] * SCALE;
  }
  __syncthreads();

#pragma unroll
  for (int h2 = 0; h2 < 2; ++h2) {
    const int bh = b * H + p + h2 * 4;
    const short8 qf = *(const short8*)(qh + ((size_t)bh * N + i0 + col) * D + quad * 8);

    float s[8][4];
#pragma unroll
    for (int c = 0; c < 8; ++c) {
      const int j0 = w * 128 + c * 16;
      const short8 kf = *(const short8*)(kh + ((size_t)bh * N + j0 + col) * D + quad * 8);
      float4v sc = {0, 0, 0, 0};
      sc = __builtin_amdgcn_mfma_f32_16x16x32_bf16(qf, kf, sc, 0, 0, 0);
      const unsigned pk = *(const unsigned*)&tileT[(size_t)(j0 + col) * 16 + quad * 4];
#pragma unroll
      for (int r = 0; r < 4; ++r) {
        const int m = quad * 4 + r;
        const unsigned by = pk >> (8 * r);
        const int e = by & 15;
        const int valid = h2 ? (by >> 4) & 1 : (by >> 5) & 1;
        const float sv = fmaf(sc[r], SCALE, qesS[h2][m][e]);
        s[c][r] = valid ? sv : -INFINITY;
      }
    }

    float mW[4];
#pragma unroll
    for (int r = 0; r < 4; ++r) {
      float m2 = s[0][r];
#pragma unroll
      for (int c = 1; c < 8; ++c) m2 = fmaxf(m2, s[c][r]);
      m2 = fmaxf(m2, __shfl_xor(m2, 1));
      m2 = fmaxf(m2, __shfl_xor(m2, 2));
      m2 = fmaxf(m2, __shfl_xor(m2, 4));
      m2 = fmaxf(m2, __shfl_xor(m2, 8));
      mW[r] = fmaxf(m2, -3.0e38f);
    }
#pragma unroll
    for (int r = 0; r < 4; ++r) {
      const int m = quad * 4 + r;
      float sm = 0.f;
#pragma unroll
      for (int c = 0; c < 8; ++c) {
        const float ex = __expf(s[c][r] - mW[r]);
        sm += ex;
        P[w][m][c * 16 + col] = (unsigned short)f2bf(ex);
      }
      sm += __shfl_xor(sm, 1);
      sm += __shfl_xor(sm, 2);
      sm += __shfl_xor(sm, 4);
      sm += __shfl_xor(sm, 8);
      if (col == 0) wlm[w][h2][m] = make_float2(mW[r], sm);
    }

    float4v o0 = {0, 0, 0, 0}, o1 = {0, 0, 0, 0};
#pragma unroll
    for (int c2 = 0; c2 < 4; ++c2) {
      const int kl = c2 * 32 + quad * 8;
      const short8 pf = *(const short8*)&P[w][col][kl];
      const int kg = w * 128 + kl;
      const short8 v0 = *(const short8*)(vt + ((size_t)bh * D + col) * N + kg);
      const short8 v1 = *(const short8*)(vt + ((size_t)bh * D + 16 + col) * N + kg);
      o0 = __builtin_amdgcn_mfma_f32_16x16x32_bf16(pf, v0, o0, 0, 0, 0);
      o1 = __builtin_amdgcn_mfma_f32_16x16x32_bf16(pf, v1, o1, 0, 0, 0);
    }
#pragma unroll
    for (int r = 0; r < 4; ++r) {
      ored[w][h2][quad * 4 + r][col] = o0[r];
      ored[w][h2][quad * 4 + r][col + 16] = o1[r];
    }
  }
  __syncthreads();

  if (t < 128) {
    const int u = t & 3, row = t >> 2, h2 = row >> 4, q = row & 15;
    const float2 s0 = wlm[0][h2][q], s1 = wlm[1][h2][q];
    const float2 s2 = wlm[2][h2][q], s3 = wlm[3][h2][q];
    const float mg = fmaxf(fmaxf(s0.x, s1.x), fmaxf(s2.x, s3.x));
    const float2 sw = (u == 0) ? s0 : (u == 1) ? s1 : (u == 2) ? s2 : s3;
    scl[u][row] = __expf(sw.x - mg);
    if (u == 0) {
      const float ls = s0.y * __expf(s0.x - mg) + s1.y * __expf(s1.x - mg) +
                       s2.y * __expf(s2.x - mg) + s3.y * __expf(s3.x - mg);
      linv[row] = 1.0f / ls;
    }
  }
  __syncthreads();

#pragma unroll
  for (int it2 = 0; it2 < 4; ++it2) {
    const int flat = it2 * 256 + t;
    const int h2 = flat >> 9, rem = flat & 511, q = rem >> 5, d = rem & 31;
    const int row = h2 * 16 + q;
    const float val = ored[0][h2][q][d] * scl[0][row] +
                      ored[1][h2][q][d] * scl[1][row] +
                      ored[2][h2][q][d] * scl[2][row] +
                      ored[3][h2][q][d] * scl[3][row];
    ctx[((size_t)(b * N) + i0 + q) * HID + (p + h2 * 4) * D + d] =
        (unsigned short)f2bf(val * linv[row]);
  }
}

}  // namespace

extern "C" void kernel_launch(void* const* d_in, const int* in_sizes, int n_in,
                              void* d_out, int out_size, void* d_ws, size_t ws_size,
                              hipStream_t stream)
{
  const float* q    = (const float*)d_in[0];
  const float* k    = (const float*)d_in[1];
  const float* v    = (const float*)d_in[2];
  const float* qemb = (const float*)d_in[3];
  const float* kemb = (const float*)d_in[4];
  const int*   ea   = (const int*)d_in[5];
  const void*  mask = d_in[6];
  const void*  fmask= d_in[7];
  const float* Wq = (const float*)d_in[8];
  const float* bq = (const float*)d_in[9];
  const float* Wk = (const float*)d_in[10];
  const float* bk = (const float*)d_in[11];
  const float* Wv = (const float*)d_in[12];
  const float* bv = (const float*)d_in[13];
  const float* Wo = (const float*)d_in[14];
  const float* bo = (const float*)d_in[15];

  // ws layout (shorts unless noted): qh|kh|vt bf16 (HSZ each), qke fp32, ctx
  // bf16, packed u8, qx|kx|vx bf16 (HSZ each), wq|wk|wv|wo bf16, flag.
  unsigned short* ws16 = (unsigned short*)d_ws;
  unsigned short* qhb = ws16;
  unsigned short* khb = qhb + HSZ;
  unsigned short* vtb = khb + HSZ;
  float* qkew = (float*)(vtb + HSZ);
  unsigned short* ctx = (unsigned short*)(qkew + (size_t)B * H * N * E);
  unsigned char* packed = (unsigned char*)(ctx + (size_t)B * N * HID);
  unsigned short* qxb = (unsigned short*)(packed + (size_t)B * N * N);
  unsigned short* kxb = qxb + HSZ;
  unsigned short* vxb = kxb + HSZ;
  unsigned short* wqb = vxb + HSZ;
  unsigned short* wkb = wqb + WSZ;
  unsigned short* wvb = wkb + WSZ;
  unsigned short* wob = wvb + WSZ;
  int* flag = (int*)(wob + WSZ);

  // 6400 conversion blocks (exact) + 1 detector block
  convert_kernel<<<6401, 256, 0, stream>>>(q, k, v, Wq, Wk, Wv, Wo,
                                           qxb, kxb, vxb, wqb, wkb, wvb, wob,
                                           (const unsigned*)fmask, flag);
  pack_kernel<<<dim3(N / 16, B), 256, 0, stream>>>(ea, mask, fmask, flag, packed);
  gemm_qkv<<<dim3((B * N) / 64, HID / 64, 3), 256, 0, stream>>>(
      qxb, kxb, vxb, wqb, wkb, wvb, bq, bk, bv, qhb, khb, vtb);
  qke_kernel<<<(B * H * N) / 16, 256, 0, stream>>>(qhb, khb, qemb, kemb, qkew);
  attn_mfma<<<dim3(N / 16, H / 2, B), 256, 0, stream>>>(qhb, khb, vtb, qkew,
                                                        packed, ctx);
  gemm_out<<<dim3((B * N) / 64, HID / 64), 256, 0, stream>>>(ctx, wob, bo, (float*)d_out);
}

// Round 8
// 212.237 us; speedup vs baseline: 2.5271x; 1.0002x over previous
//
#include <hip/hip_runtime.h>
#include <math.h>

namespace {

constexpr int B = 16, N = 512, H = 8, D = 32, E = 16, HID = 256;
constexpr float SCALE = 0.17677669529663687f;  // 32^-0.5
constexpr size_t HSZ = (size_t)B * H * N * D;  // 2,097,152 elements (= B*N*HID)
constexpr size_t WSZ = (size_t)HID * HID;      // 65,536

typedef __attribute__((ext_vector_type(8))) short short8;
typedef __attribute__((ext_vector_type(4))) float float4v;

__device__ inline short f2bf(float x) {  // fp32 -> bf16 bits, RNE (finite inputs)
  union { float f; unsigned u; } v; v.f = x;
  unsigned r = v.u + 0x7fffu + ((v.u >> 16) & 1u);
  return (short)(r >> 16);
}
__device__ inline float bf2f(unsigned short u) {
  union { unsigned u; float f; } v; v.u = ((unsigned)u) << 16; return v.f;
}

// ---------------------------------------------------------------------------
// One-shot fp32->bf16 conversion of q,k,v,Wq,Wk,Wv,Wo (exact grid: 6400 blocks
// x 256 threads x 4 elems). Last block (6400) instead runs the mask-storage
// detector: int32 0/1 data ORs to <=1, byte-packed bools OR to >1.
// ---------------------------------------------------------------------------
__global__ __launch_bounds__(256) void convert_kernel(
    const float* __restrict__ q, const float* __restrict__ k, const float* __restrict__ v,
    const float* __restrict__ Wq, const float* __restrict__ Wk,
    const float* __restrict__ Wv, const float* __restrict__ Wo,
    unsigned short* __restrict__ qx, unsigned short* __restrict__ kx,
    unsigned short* __restrict__ vx, unsigned short* __restrict__ wq,
    unsigned short* __restrict__ wk, unsigned short* __restrict__ wv,
    unsigned short* __restrict__ wo,
    const unsigned* __restrict__ fmask_u32, int* __restrict__ flag)
{
  if (blockIdx.x == gridDim.x - 1) {
    __shared__ unsigned wr[4];
    const int t = threadIdx.x, w = t >> 6, lane = t & 63;
    unsigned o = 0;
    for (int idx = t; idx < 4096; idx += 256) o |= fmask_u32[idx];
    o |= __shfl_xor(o, 1);  o |= __shfl_xor(o, 2);  o |= __shfl_xor(o, 4);
    o |= __shfl_xor(o, 8);  o |= __shfl_xor(o, 16); o |= __shfl_xor(o, 32);
    if (lane == 0) wr[w] = o;
    __syncthreads();
    if (t == 0) flag[0] = ((wr[0] | wr[1] | wr[2] | wr[3]) > 1u) ? 1 : 0;
    return;
  }
  constexpr size_t H4 = HSZ / 4;   // 524288 quads
  constexpr size_t W4 = WSZ / 4;   // 16384 quads
  const size_t idx = (size_t)blockIdx.x * 256 + threadIdx.x;
  const float* src; unsigned short* dst; size_t off;
  if (idx < H4)            { src = q; dst = qx; off = idx; }
  else if (idx < 2 * H4)   { src = k; dst = kx; off = idx - H4; }
  else if (idx < 3 * H4)   { src = v; dst = vx; off = idx - 2 * H4; }
  else {
    const size_t r = idx - 3 * H4;
    const int wsel = (int)(r / W4); off = r % W4;
    src = (wsel == 0) ? Wq : (wsel == 1) ? Wk : (wsel == 2) ? Wv : Wo;
    dst = (wsel == 0) ? wq : (wsel == 1) ? wk : (wsel == 2) ? wv : wo;
  }
  const float4 f = ((const float4*)src)[off];
  ushort4 o;
  o.x = (unsigned short)f2bf(f.x); o.y = (unsigned short)f2bf(f.y);
  o.z = (unsigned short)f2bf(f.z); o.w = (unsigned short)f2bf(f.w);
  ((ushort4*)dst)[off] = o;
}

// ---------------------------------------------------------------------------
// Fused Q/K/V projection GEMM, all-bf16 staging. z=0 -> qh headed [B,H,N,D],
// z=1 -> kh headed, z=2 -> V written TRANSPOSED [B,H,D,N] (vt) directly.
// 64x64 tile, BK=64.
// ---------------------------------------------------------------------------
__global__ __launch_bounds__(256) void gemm_qkv(
    const unsigned short* __restrict__ Xq, const unsigned short* __restrict__ Xk,
    const unsigned short* __restrict__ Xv,
    const unsigned short* __restrict__ Wq, const unsigned short* __restrict__ Wk,
    const unsigned short* __restrict__ Wv,
    const float* __restrict__ bq, const float* __restrict__ bk,
    const float* __restrict__ bv,
    unsigned short* __restrict__ qh, unsigned short* __restrict__ kh,
    unsigned short* __restrict__ vt)
{
  __shared__ __align__(16) unsigned short As[64][72];
  __shared__ __align__(16) unsigned short Bs[64][72];
  const int z = blockIdx.z;
  const unsigned short* X = (z == 0) ? Xq : (z == 1) ? Xk : Xv;
  const unsigned short* W = (z == 0) ? Wq : (z == 1) ? Wk : Wv;
  const float* bias = (z == 0) ? bq : (z == 1) ? bk : bv;

  const int m0 = blockIdx.x * 64, n0 = blockIdx.y * 64;
  const int t = threadIdx.x, lane = t & 63, w = t >> 6;
  const int quad = lane >> 4, col = lane & 15;
  const int wm = (w & 1) * 32, wn = (w >> 1) * 32;
  const int srow = t >> 2, skk = (t & 3) * 16;
  float4v acc[2][2] = {{{0,0,0,0},{0,0,0,0}},{{0,0,0,0},{0,0,0,0}}};

  for (int kit = 0; kit < 4; ++kit) {
    const int k0 = kit * 64;
    {
      const unsigned short* xp = X + (size_t)(m0 + srow) * HID + k0 + skk;
      const unsigned short* wp = W + (size_t)(n0 + srow) * HID + k0 + skk;
      *(short8*)&As[srow][skk] = *(const short8*)xp;
      *(short8*)&As[srow][skk + 8] = *(const short8*)(xp + 8);
      *(short8*)&Bs[srow][skk] = *(const short8*)wp;
      *(short8*)&Bs[srow][skk + 8] = *(const short8*)(wp + 8);
    }
    __syncthreads();
#pragma unroll
    for (int ks = 0; ks < 2; ++ks) {
      const int kk = ks * 32 + quad * 8;
      short8 a0 = *(const short8*)&As[wm + col][kk];
      short8 a1 = *(const short8*)&As[wm + 16 + col][kk];
      short8 b0 = *(const short8*)&Bs[wn + col][kk];
      short8 b1 = *(const short8*)&Bs[wn + 16 + col][kk];
      acc[0][0] = __builtin_amdgcn_mfma_f32_16x16x32_bf16(a0, b0, acc[0][0], 0, 0, 0);
      acc[0][1] = __builtin_amdgcn_mfma_f32_16x16x32_bf16(a0, b1, acc[0][1], 0, 0, 0);
      acc[1][0] = __builtin_amdgcn_mfma_f32_16x16x32_bf16(a1, b0, acc[1][0], 0, 0, 0);
      acc[1][1] = __builtin_amdgcn_mfma_f32_16x16x32_bf16(a1, b1, acc[1][1], 0, 0, 0);
    }
    __syncthreads();
  }
#pragma unroll
  for (int mt = 0; mt < 2; ++mt)
#pragma unroll
    for (int nt = 0; nt < 2; ++nt)
#pragma unroll
      for (int r = 0; r < 4; ++r) {
        const int m = m0 + wm + mt * 16 + quad * 4 + r;
        const int n = n0 + wn + nt * 16 + col;
        const float val = acc[mt][nt][r] + bias[n];
        const int b_ = m >> 9, ii = m & 511, h_ = n >> 5, d_ = n & 31;
        if (z == 2) {
          vt[((size_t)(b_ * H + h_) * D + d_) * N + ii] = (unsigned short)f2bf(val);
        } else {
          unsigned short* Yh = (z == 0) ? qh : kh;
          Yh[((size_t)(b_ * H + h_) * N + ii) * D + d_] = (unsigned short)f2bf(val);
        }
      }
}

// ---------------------------------------------------------------------------
// Output GEMM: Y = ctx(bf16) @ Wo^T(bf16) + bias, fp32 flat out. BK=64.
// ---------------------------------------------------------------------------
__global__ __launch_bounds__(256) void gemm_out(
    const unsigned short* __restrict__ X, const unsigned short* __restrict__ W,
    const float* __restrict__ bias, float* __restrict__ Yf)
{
  __shared__ __align__(16) unsigned short As[64][72];
  __shared__ __align__(16) unsigned short Bs[64][72];
  const int m0 = blockIdx.x * 64, n0 = blockIdx.y * 64;
  const int t = threadIdx.x, lane = t & 63, w = t >> 6;
  const int quad = lane >> 4, col = lane & 15;
  const int wm = (w & 1) * 32, wn = (w >> 1) * 32;
  const int srow = t >> 2, skk = (t & 3) * 16;
  float4v acc[2][2] = {{{0,0,0,0},{0,0,0,0}},{{0,0,0,0},{0,0,0,0}}};

  for (int kit = 0; kit < 4; ++kit) {
    const int k0 = kit * 64;
    {
      const unsigned short* xp = X + (size_t)(m0 + srow) * HID + k0 + skk;
      const unsigned short* wp = W + (size_t)(n0 + srow) * HID + k0 + skk;
      *(short8*)&As[srow][skk] = *(const short8*)xp;
      *(short8*)&As[srow][skk + 8] = *(const short8*)(xp + 8);
      *(short8*)&Bs[srow][skk] = *(const short8*)wp;
      *(short8*)&Bs[srow][skk + 8] = *(const short8*)(wp + 8);
    }
    __syncthreads();
#pragma unroll
    for (int ks = 0; ks < 2; ++ks) {
      const int kk = ks * 32 + quad * 8;
      short8 a0 = *(const short8*)&As[wm + col][kk];
      short8 a1 = *(const short8*)&As[wm + 16 + col][kk];
      short8 b0 = *(const short8*)&Bs[wn + col][kk];
      short8 b1 = *(const short8*)&Bs[wn + 16 + col][kk];
      acc[0][0] = __builtin_amdgcn_mfma_f32_16x16x32_bf16(a0, b0, acc[0][0], 0, 0, 0);
      acc[0][1] = __builtin_amdgcn_mfma_f32_16x16x32_bf16(a0, b1, acc[0][1], 0, 0, 0);
      acc[1][0] = __builtin_amdgcn_mfma_f32_16x16x32_bf16(a1, b0, acc[1][0], 0, 0, 0);
      acc[1][1] = __builtin_amdgcn_mfma_f32_16x16x32_bf16(a1, b1, acc[1][1], 0, 0, 0);
    }
    __syncthreads();
  }
#pragma unroll
  for (int mt = 0; mt < 2; ++mt)
#pragma unroll
    for (int nt = 0; nt < 2; ++nt)
#pragma unroll
      for (int r = 0; r < 4; ++r) {
        const int m = m0 + wm + mt * 16 + quad * 4 + r;
        const int n = n0 + wn + nt * 16 + col;
        Yf[(size_t)m * HID + n] = acc[mt][nt][r] + bias[n];
      }
}

// ---------------------------------------------------------------------------
// qke[b,h,i,e] = sum_d qh*qemb + kh*kemb  (reference gathers BOTH qe and ke
// at the query row i, so only this combined per-row table is needed).
// ---------------------------------------------------------------------------
__global__ __launch_bounds__(256) void qke_kernel(
    const unsigned short* __restrict__ qh, const unsigned short* __restrict__ kh,
    const float* __restrict__ qemb, const float* __restrict__ kemb,
    float* __restrict__ qke)
{
  __shared__ float qs[512], ks[512];
  const int t = threadIdx.x;
  const int r0 = blockIdx.x * 16;
  const size_t base = (size_t)r0 * 32;
  for (int idx = t; idx < 512; idx += 256) {
    qs[idx] = bf2f(qh[base + idx]);
    ks[idx] = bf2f(kh[base + idx]);
  }
  __syncthreads();
  const int r = t >> 4, e = t & 15;
  const int h = ((r0 + r) >> 9) & 7;
  const float* qe = qemb + e * (H * D) + h * D;
  const float* ke = kemb + e * (H * D) + h * D;
  float a = 0.f;
#pragma unroll
  for (int d = 0; d < 32; ++d)
    a += qs[r * 32 + d] * qe[d] + ks[r * 32 + d] * ke[d];
  qke[(size_t)r0 * 16 + t] = a;
}

// ---------------------------------------------------------------------------
// Pack per-pair byte tensor: packed[b][itile][j][m] = e | focal<<4 | mask<<5.
// ---------------------------------------------------------------------------
__global__ __launch_bounds__(256) void pack_kernel(
    const int* __restrict__ ea, const void* __restrict__ maskp,
    const void* __restrict__ fmaskp, const int* __restrict__ flag,
    unsigned char* __restrict__ packed)
{
  __shared__ unsigned char tl[16 * 520];
  const int it = blockIdx.x, b = blockIdx.y, t = threadIdx.x;
  const int i0 = it * 16;
  const int bf = *flag;
  const int* fm32 = (const int*)fmaskp;
  const unsigned char* fm8 = (const unsigned char*)fmaskp;
  const int* mk32 = (const int*)maskp;
  const unsigned char* mk8 = (const unsigned char*)maskp;

  for (int idx4 = t; idx4 < 2048; idx4 += 256) {
    const int m = idx4 >> 7, j4 = (idx4 & 127) * 4;
    const size_t rowoff = ((size_t)(b * N) + i0 + m) * N;
    const int4 e4 = *(const int4*)(ea + rowoff + j4);
    int fv0, fv1, fv2, fv3, mv0, mv1, mv2, mv3;
    if (bf) {
      const unsigned fw = *(const unsigned*)(fm8 + rowoff + j4);
      fv0 = fw & 0xff; fv1 = (fw >> 8) & 0xff; fv2 = (fw >> 16) & 0xff; fv3 = fw >> 24;
      const unsigned mw = *(const unsigned*)(mk8 + b * N + j4);
      mv0 = mw & 0xff; mv1 = (mw >> 8) & 0xff; mv2 = (mw >> 16) & 0xff; mv3 = mw >> 24;
    } else {
      const int4 fw = *(const int4*)(fm32 + rowoff + j4);
      fv0 = fw.x; fv1 = fw.y; fv2 = fw.z; fv3 = fw.w;
      const int4 mw = *(const int4*)(mk32 + b * N + j4);
      mv0 = mw.x; mv1 = mw.y; mv2 = mw.z; mv3 = mw.w;
    }
    const unsigned b0 = (e4.x & 15) | (fv0 ? 16u : 0u) | (mv0 ? 32u : 0u);
    const unsigned b1 = (e4.y & 15) | (fv1 ? 16u : 0u) | (mv1 ? 32u : 0u);
    const unsigned b2 = (e4.z & 15) | (fv2 ? 16u : 0u) | (mv2 ? 32u : 0u);
    const unsigned b3 = (e4.w & 15) | (fv3 ? 16u : 0u) | (mv3 ? 32u : 0u);
    *(unsigned*)&tl[m * 520 + j4] = b0 | (b1 << 8) | (b2 << 16) | (b3 << 24);
  }
  __syncthreads();
#pragma unroll
  for (int rep = 0; rep < 2; ++rep) {
    const int j = t * 2 + rep;
    unsigned wd[4];
#pragma unroll
    for (int g = 0; g < 4; ++g) {
      const unsigned c0 = tl[(g * 4 + 0) * 520 + j];
      const unsigned c1 = tl[(g * 4 + 1) * 520 + j];
      const unsigned c2 = tl[(g * 4 + 2) * 520 + j];
      const unsigned c3 = tl[(g * 4 + 3) * 520 + j];
      wd[g] = c0 | (c1 << 8) | (c2 << 16) | (c3 << 24);
    }
    *(uint4*)(packed + ((size_t)(b * 32 + it) * 512 + j) * 16) =
        make_uint4(wd[0], wd[1], wd[2], wd[3]);
  }
}

// ---------------------------------------------------------------------------
// MFMA attention, head-pair per block, wave-autonomous online softmax.
// Block = (itile, pair p, b); heads (p, p+4). Wave w owns keys [w*128,+128).
// Packed mask/edge words live in 8 VGPRs (reused for both heads) -- no LDS
// staging. 3 barriers. LDS ~38 KB -> 4 blocks/CU.
// ---------------------------------------------------------------------------
__global__ __launch_bounds__(256, 4) void attn_mfma(
    const unsigned short* __restrict__ qh, const unsigned short* __restrict__ kh,
    const unsigned short* __restrict__ vt, const float* __restrict__ qke,
    const unsigned char* __restrict__ packed, unsigned short* __restrict__ ctx)
{
  __shared__ __align__(16) unsigned short P[4][16][136];    // wave-private P
  __shared__ float qesS[2][16][17];
  __shared__ float ored[4][2][16][33];
  __shared__ float2 wlm[4][2][16];
  __shared__ float scl[4][32];
  __shared__ float linv[32];

  const int it = blockIdx.x, p = blockIdx.y, b = blockIdx.z;
  const int i0 = it * 16;
  const int t = threadIdx.x, w = t >> 6, lane = t & 63;
  const int quad = lane >> 4, col = lane & 15;

  // packed words for this wave's 128 keys -> VGPRs (coalesced 256B/16-key grp)
  unsigned pk[8];
  {
    const unsigned char* pt = packed + ((size_t)(b * 32 + it) * 512) * 16;
#pragma unroll
    for (int c = 0; c < 8; ++c)
      pk[c] = *(const unsigned*)(pt + (size_t)(w * 128 + c * 16 + col) * 16 + quad * 4);
  }
#pragma unroll
  for (int rep = 0; rep < 2; ++rep) {
    const int vi = rep * 256 + t;
    const int h2 = vi >> 8, m = (vi >> 4) & 15, e = vi & 15;
    qesS[h2][m][e] =
        qke[((size_t)(b * H + p + h2 * 4) * N + i0 + m) * E + e] * SCALE;
  }
  __syncthreads();

#pragma unroll
  for (int h2 = 0; h2 < 2; ++h2) {
    const int bh = b * H + p + h2 * 4;
    const short8 qf = *(const short8*)(qh + ((size_t)bh * N + i0 + col) * D + quad * 8);

    float s[8][4];
#pragma unroll
    for (int c = 0; c < 8; ++c) {
      const int j0 = w * 128 + c * 16;
      const short8 kf = *(const short8*)(kh + ((size_t)bh * N + j0 + col) * D + quad * 8);
      float4v sc = {0, 0, 0, 0};
      sc = __builtin_amdgcn_mfma_f32_16x16x32_bf16(qf, kf, sc, 0, 0, 0);
#pragma unroll
      for (int r = 0; r < 4; ++r) {
        const int m = quad * 4 + r;
        const unsigned by = pk[c] >> (8 * r);
        const int e = by & 15;
        const int valid = h2 ? (by >> 4) & 1 : (by >> 5) & 1;
        const float sv = fmaf(sc[r], SCALE, qesS[h2][m][e]);
        s[c][r] = valid ? sv : -INFINITY;
      }
    }

    float mW[4];
#pragma unroll
    for (int r = 0; r < 4; ++r) {
      float m2 = s[0][r];
#pragma unroll
      for (int c = 1; c < 8; ++c) m2 = fmaxf(m2, s[c][r]);
      m2 = fmaxf(m2, __shfl_xor(m2, 1));
      m2 = fmaxf(m2, __shfl_xor(m2, 2));
      m2 = fmaxf(m2, __shfl_xor(m2, 4));
      m2 = fmaxf(m2, __shfl_xor(m2, 8));
      mW[r] = fmaxf(m2, -3.0e38f);
    }
#pragma unroll
    for (int r = 0; r < 4; ++r) {
      const int m = quad * 4 + r;
      float sm = 0.f;
#pragma unroll
      for (int c = 0; c < 8; ++c) {
        const float ex = __expf(s[c][r] - mW[r]);
        sm += ex;
        P[w][m][c * 16 + col] = (unsigned short)f2bf(ex);
      }
      sm += __shfl_xor(sm, 1);
      sm += __shfl_xor(sm, 2);
      sm += __shfl_xor(sm, 4);
      sm += __shfl_xor(sm, 8);
      if (col == 0) wlm[w][h2][m] = make_float2(mW[r], sm);
    }

    float4v o0 = {0, 0, 0, 0}, o1 = {0, 0, 0, 0};
#pragma unroll
    for (int c2 = 0; c2 < 4; ++c2) {
      const int kl = c2 * 32 + quad * 8;
      const short8 pf = *(const short8*)&P[w][col][kl];
      const int kg = w * 128 + kl;
      const short8 v0 = *(const short8*)(vt + ((size_t)bh * D + col) * N + kg);
      const short8 v1 = *(const short8*)(vt + ((size_t)bh * D + 16 + col) * N + kg);
      o0 = __builtin_amdgcn_mfma_f32_16x16x32_bf16(pf, v0, o0, 0, 0, 0);
      o1 = __builtin_amdgcn_mfma_f32_16x16x32_bf16(pf, v1, o1, 0, 0, 0);
    }
#pragma unroll
    for (int r = 0; r < 4; ++r) {
      ored[w][h2][quad * 4 + r][col] = o0[r];
      ored[w][h2][quad * 4 + r][col + 16] = o1[r];
    }
  }
  __syncthreads();

  if (t < 128) {
    const int u = t & 3, row = t >> 2, h2 = row >> 4, q = row & 15;
    const float2 s0 = wlm[0][h2][q], s1 = wlm[1][h2][q];
    const float2 s2 = wlm[2][h2][q], s3 = wlm[3][h2][q];
    const float mg = fmaxf(fmaxf(s0.x, s1.x), fmaxf(s2.x, s3.x));
    const float2 sw = (u == 0) ? s0 : (u == 1) ? s1 : (u == 2) ? s2 : s3;
    scl[u][row] = __expf(sw.x - mg);
    if (u == 0) {
      const float ls = s0.y * __expf(s0.x - mg) + s1.y * __expf(s1.x - mg) +
                       s2.y * __expf(s2.x - mg) + s3.y * __expf(s3.x - mg);
      linv[row] = 1.0f / ls;
    }
  }
  __syncthreads();

#pragma unroll
  for (int it2 = 0; it2 < 4; ++it2) {
    const int flat = it2 * 256 + t;
    const int h2 = flat >> 9, rem = flat & 511, q = rem >> 5, d = rem & 31;
    const int row = h2 * 16 + q;
    const float val = ored[0][h2][q][d] * scl[0][row] +
                      ored[1][h2][q][d] * scl[1][row] +
                      ored[2][h2][q][d] * scl[2][row] +
                      ored[3][h2][q][d] * scl[3][row];
    ctx[((size_t)(b * N) + i0 + q) * HID + (p + h2 * 4) * D + d] =
        (unsigned short)f2bf(val * linv[row]);
  }
}

}  // namespace

extern "C" void kernel_launch(void* const* d_in, const int* in_sizes, int n_in,
                              void* d_out, int out_size, void* d_ws, size_t ws_size,
                              hipStream_t stream)
{
  const float* q    = (const float*)d_in[0];
  const float* k    = (const float*)d_in[1];
  const float* v    = (const float*)d_in[2];
  const float* qemb = (const float*)d_in[3];
  const float* kemb = (const float*)d_in[4];
  const int*   ea   = (const int*)d_in[5];
  const void*  mask = d_in[6];
  const void*  fmask= d_in[7];
  const float* Wq = (const float*)d_in[8];
  const float* bq = (const float*)d_in[9];
  const float* Wk = (const float*)d_in[10];
  const float* bk = (const float*)d_in[11];
  const float* Wv = (const float*)d_in[12];
  const float* bv = (const float*)d_in[13];
  const float* Wo = (const float*)d_in[14];
  const float* bo = (const float*)d_in[15];

  // ws layout (shorts unless noted): qh|kh|vt bf16 (HSZ each), qke fp32, ctx
  // bf16, packed u8, qx|kx|vx bf16 (HSZ each), wq|wk|wv|wo bf16, flag.
  unsigned short* ws16 = (unsigned short*)d_ws;
  unsigned short* qhb = ws16;
  unsigned short* khb = qhb + HSZ;
  unsigned short* vtb = khb + HSZ;
  float* qkew = (float*)(vtb + HSZ);
  unsigned short* ctx = (unsigned short*)(qkew + (size_t)B * H * N * E);
  unsigned char* packed = (unsigned char*)(ctx + (size_t)B * N * HID);
  unsigned short* qxb = (unsigned short*)(packed + (size_t)B * N * N);
  unsigned short* kxb = qxb + HSZ;
  unsigned short* vxb = kxb + HSZ;
  unsigned short* wqb = vxb + HSZ;
  unsigned short* wkb = wqb + WSZ;
  unsigned short* wvb = wkb + WSZ;
  unsigned short* wob = wvb + WSZ;
  int* flag = (int*)(wob + WSZ);

  convert_kernel<<<6401, 256, 0, stream>>>(q, k, v, Wq, Wk, Wv, Wo,
                                           qxb, kxb, vxb, wqb, wkb, wvb, wob,
                                           (const unsigned*)fmask, flag);
  pack_kernel<<<dim3(N / 16, B), 256, 0, stream>>>(ea, mask, fmask, flag, packed);
  gemm_qkv<<<dim3((B * N) / 64, HID / 64, 3), 256, 0, stream>>>(
      qxb, kxb, vxb, wqb, wkb, wvb, bq, bk, bv, qhb, khb, vtb);
  qke_kernel<<<(B * H * N) / 16, 256, 0, stream>>>(qhb, khb, qemb, kemb, qkew);
  attn_mfma<<<dim3(N / 16, H / 2, B), 256, 0, stream>>>(qhb, khb, vtb, qkew,
                                                        packed, ctx);
  gemm_out<<<dim3((B * N) / 64, HID / 64), 256, 0, stream>>>(ctx, wob, bo, (float*)d_out);
}

// Round 9
// 181.884 us; speedup vs baseline: 2.9488x; 1.1669x over previous
//
#include <hip/hip_runtime.h>
#include <math.h>

namespace {

constexpr int B = 16, N = 512, H = 8, D = 32, E = 16, HID = 256;
constexpr float SCALE = 0.17677669529663687f;  // 32^-0.5
constexpr size_t HSZ = (size_t)B * H * N * D;  // 2,097,152 elements (= B*N*HID)
constexpr size_t WSZ = (size_t)HID * HID;      // 65,536
constexpr int CONV_BLOCKS = 6400;              // (3*HSZ + 4*WSZ)/4 elems / 256

typedef __attribute__((ext_vector_type(8))) short short8;
typedef __attribute__((ext_vector_type(4))) float float4v;

__device__ inline short f2bf(float x) {  // fp32 -> bf16 bits, RNE (finite inputs)
  union { float f; unsigned u; } v; v.f = x;
  unsigned r = v.u + 0x7fffu + ((v.u >> 16) & 1u);
  return (short)(r >> 16);
}
__device__ inline float bf2f(unsigned short u) {
  union { unsigned u; float f; } v; v.u = ((unsigned)u) << 16; return v.f;
}

// ---------------------------------------------------------------------------
// Mega-prep (one launch):
//  blocks [0,6400): fp32->bf16 convert of q,k,v,Wq,Wk,Wv,Wo (4 elems/thread)
//  blocks [6400,6912): pack tiles: packed[b][it][j][m] = e | focal<<4|mask<<5.
//    Each pack block self-detects mask storage (int32 0/1 words OR to <=1;
//    byte-packed bools OR to >1) from the first 4KB of fmask -- no cross-
//    kernel flag dependency.
// ---------------------------------------------------------------------------
__global__ __launch_bounds__(256) void prep_kernel(
    const float* __restrict__ q, const float* __restrict__ k, const float* __restrict__ v,
    const float* __restrict__ Wq, const float* __restrict__ Wk,
    const float* __restrict__ Wv, const float* __restrict__ Wo,
    unsigned short* __restrict__ qx, unsigned short* __restrict__ kx,
    unsigned short* __restrict__ vx, unsigned short* __restrict__ wq,
    unsigned short* __restrict__ wk, unsigned short* __restrict__ wv,
    unsigned short* __restrict__ wo,
    const int* __restrict__ ea, const void* __restrict__ maskp,
    const void* __restrict__ fmaskp, unsigned char* __restrict__ packed)
{
  __shared__ unsigned char tl[16 * 520];
  __shared__ unsigned sdet[4];
  const int bid = blockIdx.x, t = threadIdx.x;

  if (bid < CONV_BLOCKS) {
    constexpr size_t H4 = HSZ / 4;
    constexpr size_t W4 = WSZ / 4;
    const size_t idx = (size_t)bid * 256 + t;
    const float* src; unsigned short* dst; size_t off;
    if (idx < H4)            { src = q; dst = qx; off = idx; }
    else if (idx < 2 * H4)   { src = k; dst = kx; off = idx - H4; }
    else if (idx < 3 * H4)   { src = v; dst = vx; off = idx - 2 * H4; }
    else {
      const size_t r = idx - 3 * H4;
      const int wsel = (int)(r / W4); off = r % W4;
      src = (wsel == 0) ? Wq : (wsel == 1) ? Wk : (wsel == 2) ? Wv : Wo;
      dst = (wsel == 0) ? wq : (wsel == 1) ? wk : (wsel == 2) ? wv : wo;
    }
    const float4 f = ((const float4*)src)[off];
    ushort4 o;
    o.x = (unsigned short)f2bf(f.x); o.y = (unsigned short)f2bf(f.y);
    o.z = (unsigned short)f2bf(f.z); o.w = (unsigned short)f2bf(f.w);
    ((ushort4*)dst)[off] = o;
    return;
  }

  // ---- pack branch ----
  const int pb = bid - CONV_BLOCKS;
  const int it = pb & 31, b = pb >> 5;
  const int i0 = it * 16;
  const int w = t >> 6, lane = t & 63;
  const unsigned* fm_u = (const unsigned*)fmaskp;
  // self-detect storage format (first 1024 words = 4KB)
  unsigned o = 0;
#pragma unroll
  for (int i = 0; i < 4; ++i) o |= fm_u[t + i * 256];
  o |= __shfl_xor(o, 1);  o |= __shfl_xor(o, 2);  o |= __shfl_xor(o, 4);
  o |= __shfl_xor(o, 8);  o |= __shfl_xor(o, 16); o |= __shfl_xor(o, 32);
  if (lane == 0) sdet[w] = o;
  __syncthreads();
  const int bf = ((sdet[0] | sdet[1] | sdet[2] | sdet[3]) > 1u) ? 1 : 0;

  const int* fm32 = (const int*)fmaskp;
  const unsigned char* fm8 = (const unsigned char*)fmaskp;
  const int* mk32 = (const int*)maskp;
  const unsigned char* mk8 = (const unsigned char*)maskp;

  for (int idx4 = t; idx4 < 2048; idx4 += 256) {
    const int m = idx4 >> 7, j4 = (idx4 & 127) * 4;
    const size_t rowoff = ((size_t)(b * N) + i0 + m) * N;
    const int4 e4 = *(const int4*)(ea + rowoff + j4);
    int fv0, fv1, fv2, fv3, mv0, mv1, mv2, mv3;
    if (bf) {
      const unsigned fw = *(const unsigned*)(fm8 + rowoff + j4);
      fv0 = fw & 0xff; fv1 = (fw >> 8) & 0xff; fv2 = (fw >> 16) & 0xff; fv3 = fw >> 24;
      const unsigned mw = *(const unsigned*)(mk8 + b * N + j4);
      mv0 = mw & 0xff; mv1 = (mw >> 8) & 0xff; mv2 = (mw >> 16) & 0xff; mv3 = mw >> 24;
    } else {
      const int4 fw = *(const int4*)(fm32 + rowoff + j4);
      fv0 = fw.x; fv1 = fw.y; fv2 = fw.z; fv3 = fw.w;
      const int4 mw = *(const int4*)(mk32 + b * N + j4);
      mv0 = mw.x; mv1 = mw.y; mv2 = mw.z; mv3 = mw.w;
    }
    const unsigned b0 = (e4.x & 15) | (fv0 ? 16u : 0u) | (mv0 ? 32u : 0u);
    const unsigned b1 = (e4.y & 15) | (fv1 ? 16u : 0u) | (mv1 ? 32u : 0u);
    const unsigned b2 = (e4.z & 15) | (fv2 ? 16u : 0u) | (mv2 ? 32u : 0u);
    const unsigned b3 = (e4.w & 15) | (fv3 ? 16u : 0u) | (mv3 ? 32u : 0u);
    *(unsigned*)&tl[m * 520 + j4] = b0 | (b1 << 8) | (b2 << 16) | (b3 << 24);
  }
  __syncthreads();
#pragma unroll
  for (int rep = 0; rep < 2; ++rep) {
    const int j = t * 2 + rep;
    unsigned wd[4];
#pragma unroll
    for (int g = 0; g < 4; ++g) {
      const unsigned c0 = tl[(g * 4 + 0) * 520 + j];
      const unsigned c1 = tl[(g * 4 + 1) * 520 + j];
      const unsigned c2 = tl[(g * 4 + 2) * 520 + j];
      const unsigned c3 = tl[(g * 4 + 3) * 520 + j];
      wd[g] = c0 | (c1 << 8) | (c2 << 16) | (c3 << 24);
    }
    *(uint4*)(packed + ((size_t)(b * 32 + it) * 512 + j) * 16) =
        make_uint4(wd[0], wd[1], wd[2], wd[3]);
  }
}

// ---------------------------------------------------------------------------
// Fused Q/K/V projection GEMM, all-bf16 staging. z=0 -> qh headed [B,H,N,D],
// z=1 -> kh headed, z=2 -> V transposed [B,H,D,N] via LDS tile (coalesced).
// 64x64 tile, BK=64.
// ---------------------------------------------------------------------------
__global__ __launch_bounds__(256) void gemm_qkv(
    const unsigned short* __restrict__ Xq, const unsigned short* __restrict__ Xk,
    const unsigned short* __restrict__ Xv,
    const unsigned short* __restrict__ Wq, const unsigned short* __restrict__ Wk,
    const unsigned short* __restrict__ Wv,
    const float* __restrict__ bq, const float* __restrict__ bk,
    const float* __restrict__ bv,
    unsigned short* __restrict__ qh, unsigned short* __restrict__ kh,
    unsigned short* __restrict__ vt)
{
  __shared__ __align__(16) unsigned short As[64][72];
  __shared__ __align__(16) unsigned short Bs[64][72];
  const int z = blockIdx.z;
  const unsigned short* X = (z == 0) ? Xq : (z == 1) ? Xk : Xv;
  const unsigned short* W = (z == 0) ? Wq : (z == 1) ? Wk : Wv;
  const float* bias = (z == 0) ? bq : (z == 1) ? bk : bv;

  const int m0 = blockIdx.x * 64, n0 = blockIdx.y * 64;
  const int t = threadIdx.x, lane = t & 63, w = t >> 6;
  const int quad = lane >> 4, col = lane & 15;
  const int wm = (w & 1) * 32, wn = (w >> 1) * 32;
  const int srow = t >> 2, skk = (t & 3) * 16;
  float4v acc[2][2] = {{{0,0,0,0},{0,0,0,0}},{{0,0,0,0},{0,0,0,0}}};

  for (int kit = 0; kit < 4; ++kit) {
    const int k0 = kit * 64;
    {
      const unsigned short* xp = X + (size_t)(m0 + srow) * HID + k0 + skk;
      const unsigned short* wp = W + (size_t)(n0 + srow) * HID + k0 + skk;
      *(short8*)&As[srow][skk] = *(const short8*)xp;
      *(short8*)&As[srow][skk + 8] = *(const short8*)(xp + 8);
      *(short8*)&Bs[srow][skk] = *(const short8*)wp;
      *(short8*)&Bs[srow][skk + 8] = *(const short8*)(wp + 8);
    }
    __syncthreads();
#pragma unroll
    for (int ks = 0; ks < 2; ++ks) {
      const int kk = ks * 32 + quad * 8;
      short8 a0 = *(const short8*)&As[wm + col][kk];
      short8 a1 = *(const short8*)&As[wm + 16 + col][kk];
      short8 b0 = *(const short8*)&Bs[wn + col][kk];
      short8 b1 = *(const short8*)&Bs[wn + 16 + col][kk];
      acc[0][0] = __builtin_amdgcn_mfma_f32_16x16x32_bf16(a0, b0, acc[0][0], 0, 0, 0);
      acc[0][1] = __builtin_amdgcn_mfma_f32_16x16x32_bf16(a0, b1, acc[0][1], 0, 0, 0);
      acc[1][0] = __builtin_amdgcn_mfma_f32_16x16x32_bf16(a1, b0, acc[1][0], 0, 0, 0);
      acc[1][1] = __builtin_amdgcn_mfma_f32_16x16x32_bf16(a1, b1, acc[1][1], 0, 0, 0);
    }
    __syncthreads();
  }
  if (z == 2) {
    // stage outputs transposed in LDS (As free after last barrier), then
    // write vt rows coalesced: consecutive lanes -> consecutive ii.
#pragma unroll
    for (int mt = 0; mt < 2; ++mt)
#pragma unroll
      for (int nt = 0; nt < 2; ++nt)
#pragma unroll
        for (int r = 0; r < 4; ++r) {
          const int m_l = wm + mt * 16 + quad * 4 + r;
          const int n_l = wn + nt * 16 + col;
          As[n_l][m_l] = (unsigned short)f2bf(acc[mt][nt][r] + bias[n0 + n_l]);
        }
    __syncthreads();
#pragma unroll
    for (int rep = 0; rep < 16; ++rep) {
      const int flat = rep * 256 + t;
      const int n_l = flat >> 6, m_l = flat & 63;
      const int n = n0 + n_l, m = m0 + m_l;
      const int b_ = m >> 9, ii = m & 511, h_ = n >> 5, d_ = n & 31;
      vt[((size_t)(b_ * H + h_) * D + d_) * N + ii] = As[n_l][m_l];
    }
    return;
  }
#pragma unroll
  for (int mt = 0; mt < 2; ++mt)
#pragma unroll
    for (int nt = 0; nt < 2; ++nt)
#pragma unroll
      for (int r = 0; r < 4; ++r) {
        const int m = m0 + wm + mt * 16 + quad * 4 + r;
        const int n = n0 + wn + nt * 16 + col;
        const float val = acc[mt][nt][r] + bias[n];
        const int b_ = m >> 9, ii = m & 511, h_ = n >> 5, d_ = n & 31;
        unsigned short* Yh = (z == 0) ? qh : kh;
        Yh[((size_t)(b_ * H + h_) * N + ii) * D + d_] = (unsigned short)f2bf(val);
      }
}

// ---------------------------------------------------------------------------
// Output GEMM: Y = ctx(bf16) @ Wo^T(bf16) + bias, fp32 flat out. BK=64.
// ---------------------------------------------------------------------------
__global__ __launch_bounds__(256) void gemm_out(
    const unsigned short* __restrict__ X, const unsigned short* __restrict__ W,
    const float* __restrict__ bias, float* __restrict__ Yf)
{
  __shared__ __align__(16) unsigned short As[64][72];
  __shared__ __align__(16) unsigned short Bs[64][72];
  const int m0 = blockIdx.x * 64, n0 = blockIdx.y * 64;
  const int t = threadIdx.x, lane = t & 63, w = t >> 6;
  const int quad = lane >> 4, col = lane & 15;
  const int wm = (w & 1) * 32, wn = (w >> 1) * 32;
  const int srow = t >> 2, skk = (t & 3) * 16;
  float4v acc[2][2] = {{{0,0,0,0},{0,0,0,0}},{{0,0,0,0},{0,0,0,0}}};

  for (int kit = 0; kit < 4; ++kit) {
    const int k0 = kit * 64;
    {
      const unsigned short* xp = X + (size_t)(m0 + srow) * HID + k0 + skk;
      const unsigned short* wp = W + (size_t)(n0 + srow) * HID + k0 + skk;
      *(short8*)&As[srow][skk] = *(const short8*)xp;
      *(short8*)&As[srow][skk + 8] = *(const short8*)(xp + 8);
      *(short8*)&Bs[srow][skk] = *(const short8*)wp;
      *(short8*)&Bs[srow][skk + 8] = *(const short8*)(wp + 8);
    }
    __syncthreads();
#pragma unroll
    for (int ks = 0; ks < 2; ++ks) {
      const int kk = ks * 32 + quad * 8;
      short8 a0 = *(const short8*)&As[wm + col][kk];
      short8 a1 = *(const short8*)&As[wm + 16 + col][kk];
      short8 b0 = *(const short8*)&Bs[wn + col][kk];
      short8 b1 = *(const short8*)&Bs[wn + 16 + col][kk];
      acc[0][0] = __builtin_amdgcn_mfma_f32_16x16x32_bf16(a0, b0, acc[0][0], 0, 0, 0);
      acc[0][1] = __builtin_amdgcn_mfma_f32_16x16x32_bf16(a0, b1, acc[0][1], 0, 0, 0);
      acc[1][0] = __builtin_amdgcn_mfma_f32_16x16x32_bf16(a1, b0, acc[1][0], 0, 0, 0);
      acc[1][1] = __builtin_amdgcn_mfma_f32_16x16x32_bf16(a1, b1, acc[1][1], 0, 0, 0);
    }
    __syncthreads();
  }
#pragma unroll
  for (int mt = 0; mt < 2; ++mt)
#pragma unroll
    for (int nt = 0; nt < 2; ++nt)
#pragma unroll
      for (int r = 0; r < 4; ++r) {
        const int m = m0 + wm + mt * 16 + quad * 4 + r;
        const int n = n0 + wn + nt * 16 + col;
        Yf[(size_t)m * HID + n] = acc[mt][nt][r] + bias[n];
      }
}

// ---------------------------------------------------------------------------
// MFMA attention, head-pair per block, wave-autonomous online softmax.
// qes (edge-bias table) computed in-kernel from qh/kh rows + emb slices, in
// LDS scratch ALIASED over the P buffer (P is dead until after prologue).
// Packed mask/edge words in 8 VGPRs. 4 barriers total.
// ---------------------------------------------------------------------------
__global__ __launch_bounds__(256) void attn_mfma(
    const unsigned short* __restrict__ qh, const unsigned short* __restrict__ kh,
    const unsigned short* __restrict__ vt,
    const float* __restrict__ qemb, const float* __restrict__ kemb,
    const unsigned char* __restrict__ packed, unsigned short* __restrict__ ctx)
{
  __shared__ __align__(16) unsigned short P[4][16][136];    // 17408 B
  __shared__ float qesS[2][16][17];
  __shared__ float ored[4][2][16][33];
  __shared__ float2 wlm[4][2][16];
  __shared__ float scl[4][32];
  __shared__ float linv[32];

  const int it = blockIdx.x, p = blockIdx.y, b = blockIdx.z;
  const int i0 = it * 16;
  const int t = threadIdx.x, w = t >> 6, lane = t & 63;
  const int quad = lane >> 4, col = lane & 15;

  // prologue scratch aliases P: qrow@0, krow@1024, eq@2048, ek@3072 (shorts)
  unsigned short* SCR = &P[0][0][0];

  // packed words for this wave's 128 keys -> VGPRs
  unsigned pk[8];
  {
    const unsigned char* pt = packed + ((size_t)(b * 32 + it) * 512) * 16;
#pragma unroll
    for (int c = 0; c < 8; ++c)
      pk[c] = *(const unsigned*)(pt + (size_t)(w * 128 + c * 16 + col) * 16 + quad * 4);
  }
  {
    // stage qh/kh rows (bf16): 64 rows x 32, 8 shorts per thread-part
    const int rr = t >> 2, part = t & 3;
    const int h2r = (rr & 31) >> 4, mr = rr & 15;
    const unsigned short* src = (rr < 32) ? qh : kh;
    const short8 vv = *(const short8*)(
        src + ((size_t)(b * H + p + h2r * 4) * N + i0 + mr) * D + part * 8);
    *(short8*)(SCR + rr * 32 + part * 8) = vv;
    // stage emb slices (fp32 -> bf16): eq/ek [h2][e][32]
    const int er = rr;
    const int h2e = (er & 31) >> 4, ee = er & 15;
    const float* emb = (er < 32) ? qemb : kemb;
    const float* sp = emb + ee * 256 + (p + h2e * 4) * 32 + part * 8;
    const float4 f1 = *(const float4*)sp, f2 = *(const float4*)(sp + 4);
    short8 ov;
    ov[0] = f2bf(f1.x); ov[1] = f2bf(f1.y); ov[2] = f2bf(f1.z); ov[3] = f2bf(f1.w);
    ov[4] = f2bf(f2.x); ov[5] = f2bf(f2.y); ov[6] = f2bf(f2.z); ov[7] = f2bf(f2.w);
    *(short8*)(SCR + 2048 + er * 32 + part * 8) = ov;
  }
  __syncthreads();
  // qes[h2][m][e] = sum_d qrow*eq + krow*ek  (SCALE folded)
#pragma unroll
  for (int rep = 0; rep < 2; ++rep) {
    const int vi = rep * 256 + t;
    const int h2 = vi >> 8, m = (vi >> 4) & 15, e = vi & 15;
    float a = 0.f;
#pragma unroll
    for (int dv = 0; dv < 4; ++dv) {
      const short8 qr = *(const short8*)(SCR + h2 * 512 + m * 32 + dv * 8);
      const short8 kr = *(const short8*)(SCR + 1024 + h2 * 512 + m * 32 + dv * 8);
      const short8 eq = *(const short8*)(SCR + 2048 + (h2 * 16 + e) * 32 + dv * 8);
      const short8 ek = *(const short8*)(SCR + 3072 + (h2 * 16 + e) * 32 + dv * 8);
#pragma unroll
      for (int j = 0; j < 8; ++j)
        a += bf2f((unsigned short)qr[j]) * bf2f((unsigned short)eq[j]) +
             bf2f((unsigned short)kr[j]) * bf2f((unsigned short)ek[j]);
    }
    qesS[h2][m][e] = a * SCALE;
  }
  __syncthreads();   // qesS ready; SCR (=P) now reusable by waves

#pragma unroll
  for (int h2 = 0; h2 < 2; ++h2) {
    const int bh = b * H + p + h2 * 4;
    const short8 qf = *(const short8*)(qh + ((size_t)bh * N + i0 + col) * D + quad * 8);

    float s[8][4];
#pragma unroll
    for (int c = 0; c < 8; ++c) {
      const int j0 = w * 128 + c * 16;
      const short8 kf = *(const short8*)(kh + ((size_t)bh * N + j0 + col) * D + quad * 8);
      float4v sc = {0, 0, 0, 0};
      sc = __builtin_amdgcn_mfma_f32_16x16x32_bf16(qf, kf, sc, 0, 0, 0);
#pragma unroll
      for (int r = 0; r < 4; ++r) {
        const int m = quad * 4 + r;
        const unsigned by = pk[c] >> (8 * r);
        const int e = by & 15;
        const int valid = h2 ? (by >> 4) & 1 : (by >> 5) & 1;
        const float sv = fmaf(sc[r], SCALE, qesS[h2][m][e]);
        s[c][r] = valid ? sv : -INFINITY;
      }
    }

    float mW[4];
#pragma unroll
    for (int r = 0; r < 4; ++r) {
      float m2 = s[0][r];
#pragma unroll
      for (int c = 1; c < 8; ++c) m2 = fmaxf(m2, s[c][r]);
      m2 = fmaxf(m2, __shfl_xor(m2, 1));
      m2 = fmaxf(m2, __shfl_xor(m2, 2));
      m2 = fmaxf(m2, __shfl_xor(m2, 4));
      m2 = fmaxf(m2, __shfl_xor(m2, 8));
      mW[r] = fmaxf(m2, -3.0e38f);
    }
#pragma unroll
    for (int r = 0; r < 4; ++r) {
      const int m = quad * 4 + r;
      float sm = 0.f;
#pragma unroll
      for (int c = 0; c < 8; ++c) {
        const float ex = __expf(s[c][r] - mW[r]);
        sm += ex;
        P[w][m][c * 16 + col] = (unsigned short)f2bf(ex);
      }
      sm += __shfl_xor(sm, 1);
      sm += __shfl_xor(sm, 2);
      sm += __shfl_xor(sm, 4);
      sm += __shfl_xor(sm, 8);
      if (col == 0) wlm[w][h2][m] = make_float2(mW[r], sm);
    }

    float4v o0 = {0, 0, 0, 0}, o1 = {0, 0, 0, 0};
#pragma unroll
    for (int c2 = 0; c2 < 4; ++c2) {
      const int kl = c2 * 32 + quad * 8;
      const short8 pf = *(const short8*)&P[w][col][kl];
      const int kg = w * 128 + kl;
      const short8 v0 = *(const short8*)(vt + ((size_t)bh * D + col) * N + kg);
      const short8 v1 = *(const short8*)(vt + ((size_t)bh * D + 16 + col) * N + kg);
      o0 = __builtin_amdgcn_mfma_f32_16x16x32_bf16(pf, v0, o0, 0, 0, 0);
      o1 = __builtin_amdgcn_mfma_f32_16x16x32_bf16(pf, v1, o1, 0, 0, 0);
    }
#pragma unroll
    for (int r = 0; r < 4; ++r) {
      ored[w][h2][quad * 4 + r][col] = o0[r];
      ored[w][h2][quad * 4 + r][col + 16] = o1[r];
    }
  }
  __syncthreads();

  if (t < 128) {
    const int u = t & 3, row = t >> 2, h2 = row >> 4, q = row & 15;
    const float2 s0 = wlm[0][h2][q], s1 = wlm[1][h2][q];
    const float2 s2 = wlm[2][h2][q], s3 = wlm[3][h2][q];
    const float mg = fmaxf(fmaxf(s0.x, s1.x), fmaxf(s2.x, s3.x));
    const float2 sw = (u == 0) ? s0 : (u == 1) ? s1 : (u == 2) ? s2 : s3;
    scl[u][row] = __expf(sw.x - mg);
    if (u == 0) {
      const float ls = s0.y * __expf(s0.x - mg) + s1.y * __expf(s1.x - mg) +
                       s2.y * __expf(s2.x - mg) + s3.y * __expf(s3.x - mg);
      linv[row] = 1.0f / ls;
    }
  }
  __syncthreads();

#pragma unroll
  for (int it2 = 0; it2 < 4; ++it2) {
    const int flat = it2 * 256 + t;
    const int h2 = flat >> 9, rem = flat & 511, q2 = rem >> 5, d = rem & 31;
    const int row = h2 * 16 + q2;
    const float val = ored[0][h2][q2][d] * scl[0][row] +
                      ored[1][h2][q2][d] * scl[1][row] +
                      ored[2][h2][q2][d] * scl[2][row] +
                      ored[3][h2][q2][d] * scl[3][row];
    ctx[((size_t)(b * N) + i0 + q2) * HID + (p + h2 * 4) * D + d] =
        (unsigned short)f2bf(val * linv[row]);
  }
}

}  // namespace

extern "C" void kernel_launch(void* const* d_in, const int* in_sizes, int n_in,
                              void* d_out, int out_size, void* d_ws, size_t ws_size,
                              hipStream_t stream)
{
  const float* q    = (const float*)d_in[0];
  const float* k    = (const float*)d_in[1];
  const float* v    = (const float*)d_in[2];
  const float* qemb = (const float*)d_in[3];
  const float* kemb = (const float*)d_in[4];
  const int*   ea   = (const int*)d_in[5];
  const void*  mask = d_in[6];
  const void*  fmask= d_in[7];
  const float* Wq = (const float*)d_in[8];
  const float* bq = (const float*)d_in[9];
  const float* Wk = (const float*)d_in[10];
  const float* bk = (const float*)d_in[11];
  const float* Wv = (const float*)d_in[12];
  const float* bv = (const float*)d_in[13];
  const float* Wo = (const float*)d_in[14];
  const float* bo = (const float*)d_in[15];

  // ws layout: qh|kh|vt bf16 (HSZ each), ctx bf16, packed u8,
  // qx|kx|vx bf16 (HSZ each), wq|wk|wv|wo bf16.
  unsigned short* ws16 = (unsigned short*)d_ws;
  unsigned short* qhb = ws16;
  unsigned short* khb = qhb + HSZ;
  unsigned short* vtb = khb + HSZ;
  unsigned short* ctx = vtb + HSZ;
  unsigned char* packed = (unsigned char*)(ctx + (size_t)B * N * HID);
  unsigned short* qxb = (unsigned short*)(packed + (size_t)B * N * N);
  unsigned short* kxb = qxb + HSZ;
  unsigned short* vxb = kxb + HSZ;
  unsigned short* wqb = vxb + HSZ;
  unsigned short* wkb = wqb + WSZ;
  unsigned short* wvb = wkb + WSZ;
  unsigned short* wob = wvb + WSZ;

  prep_kernel<<<CONV_BLOCKS + 512, 256, 0, stream>>>(
      q, k, v, Wq, Wk, Wv, Wo, qxb, kxb, vxb, wqb, wkb, wvb, wob,
      ea, mask, fmask, packed);
  gemm_qkv<<<dim3((B * N) / 64, HID / 64, 3), 256, 0, stream>>>(
      qxb, kxb, vxb, wqb, wkb, wvb, bq, bk, bv, qhb, khb, vtb);
  attn_mfma<<<dim3(N / 16, H / 2, B), 256, 0, stream>>>(qhb, khb, vtb, qemb,
                                                        kemb, packed, ctx);
  gemm_out<<<dim3((B * N) / 64, HID / 64), 256, 0, stream>>>(ctx, wob, bo, (float*)d_out);
}